// Round 14
// baseline (454.537 us; speedup 1.0000x reference)
//
#include <hip/hip_runtime.h>

// ---------------------------------------------------------------------------
// BiNet R14 = R13 with the build pipeline collapsed (k_mfma frozen at 79us):
//   R13: 8 dispatches, ~117us build vs 79us compute. Fusions:
//   * k_init -> one 4KB memset (hist|gcur|cur); node_order init eliminated
//     via pbs[4]-bounded k_mfma + assign block0 writing the <=124 pad holes.
//   * k_bscan -> folded into passB2 (block-reduce gcur[0..b) locally).
//   * k_padscan2 -> folded into assign (each block recomputes the 256-bin
//     padded scan in LDS; global zeroed cur[] gives cross-block ranks).
//   * k_precomp fused into the assign launch (independent work, stage dead).
//   Fast path: memset + passA + passB2 + tail(assign+precomp) + mfma.
// ---------------------------------------------------------------------------

#define IN_C 32
#define IN_F 68
#define TILE_A 4096
#define BK_SHIFT 9
#define NBKT_MAX 448
#define BCAP 6144

using bf16x8v = __attribute__((ext_vector_type(8))) short;
using f32x16v = __attribute__((ext_vector_type(16))) float;
using f32x2v  = __attribute__((ext_vector_type(2))) float;

union U4F { unsigned u[4]; bf16x8v v; };

__device__ __forceinline__ unsigned cvtpk_bf16(float a, float b) {
    unsigned r;
    asm("v_cvt_pk_bf16_f32 %0, %1, %2" : "=v"(r) : "v"(a), "v"(b));
    return r;
}
__device__ __forceinline__ float bflo(unsigned u) { return __uint_as_float(u << 16); }
__device__ __forceinline__ float bfhi(unsigned u) { return __uint_as_float(u & 0xffff0000u); }

__device__ __forceinline__ float angf(float ax, float ay, float az,
                                      float bx, float by, float bz) {
    float cx = ay * bz - az * by;
    float cy = az * bx - ax * bz;
    float cz = ax * by - ay * bx;
    float cn = sqrtf(cx * cx + cy * cy + cz * cz);
    float dt = ax * bx + ay * by + az * bz;
    return atan2f(cn, dt);
}

__device__ __forceinline__ int branch_of(int m) {
    if (m == 0 || m == 10) return 0;
    if (m == 1 || m == 9)  return 1;
    if (m >= 2 && m <= 5)  return 2;
    return 3;
}

__device__ __forceinline__ unsigned bf16r(float f) {
    unsigned u = __float_as_uint(f);
    return (u + 0x7fffu + ((u >> 16) & 1u)) >> 16;
}

// ======================= shared precompute body ==============================
// fp8mode: yrec[g][src] = 64B {fp8 yp 32B | bf16 geo 12B | pad}. else bf16 yp.
__device__ __forceinline__ void precomp_body(
    int t,
    const float* __restrict__ x_prot, const float* __restrict__ x_dna,
    const float* __restrict__ v_prot, const float* __restrict__ prot_vec,
    const float* __restrict__ W1, const float* __restrict__ b1,
    int NP, int NPpad, int NB, int NBpad, int do_dna, int fp8mode,
    unsigned* __restrict__ yrec, unsigned short* __restrict__ ypb,
    unsigned short* __restrict__ yd)
{
    int NP4 = 4 * NPpad;
    float h[IN_C];

    if (t < NP4) {
        int g = t / NPpad;
        int p = t - g * NPpad;
        if (p >= NP) return;
        int bb = __builtin_amdgcn_readfirstlane(g);
        const float* Wa = W1 + bb * (IN_F * IN_C);
        #pragma unroll
        for (int c = 0; c < IN_C; ++c) h[c] = 0.0f;
        const float4* xp = reinterpret_cast<const float4*>(x_prot + (size_t)p * IN_C);
        #pragma unroll
        for (int kk = 0; kk < 8; ++kk) {
            float4 xv = xp[kk];
            float fs[4] = {xv.x, xv.y, xv.z, xv.w};
            #pragma unroll
            for (int j = 0; j < 4; ++j)
                #pragma unroll
                for (int c = 0; c < IN_C; ++c)
                    h[c] = fmaf(fs[j], Wa[(kk * 4 + j) * IN_C + c], h[c]);
        }
        if (fp8mode) {
            unsigned yw[8];
            #pragma unroll
            for (int j = 0; j < 8; ++j) {
                int w = 0;
                w = __builtin_amdgcn_cvt_pk_fp8_f32(h[4 * j],     h[4 * j + 1], w, false);
                w = __builtin_amdgcn_cvt_pk_fp8_f32(h[4 * j + 2], h[4 * j + 3], w, true);
                yw[j] = (unsigned)w;
            }
            float vpx = v_prot[p * 3 + 0], vpy = v_prot[p * 3 + 1], vpz = v_prot[p * 3 + 2];
            float njx = prot_vec[p * 3 + 0], njy = prot_vec[p * 3 + 1], njz = prot_vec[p * 3 + 2];
            uint4 gr;
            gr.x = bf16r(vpx) | (bf16r(vpy) << 16);
            gr.y = bf16r(vpz) | (bf16r(njx) << 16);
            gr.z = bf16r(njy) | (bf16r(njz) << 16);
            gr.w = 0;
            uint4* d4 = reinterpret_cast<uint4*>(yrec + ((size_t)bb * NP + p) * 16);
            d4[0] = make_uint4(yw[0], yw[1], yw[2], yw[3]);
            d4[1] = make_uint4(yw[4], yw[5], yw[6], yw[7]);
            d4[2] = gr;
        } else {
            unsigned yw[16];
            #pragma unroll
            for (int j = 0; j < 16; ++j)
                yw[j] = bf16r(h[2 * j]) | (bf16r(h[2 * j + 1]) << 16);
            uint4* d4 = reinterpret_cast<uint4*>(ypb + ((size_t)bb * NP + p) * IN_C);
            d4[0] = make_uint4(yw[0], yw[1], yw[2], yw[3]);
            d4[1] = make_uint4(yw[4], yw[5], yw[6], yw[7]);
            d4[2] = make_uint4(yw[8], yw[9], yw[10], yw[11]);
            d4[3] = make_uint4(yw[12], yw[13], yw[14], yw[15]);
        }
    } else {
        if (!do_dna) return;
        int t2 = t - NP4;
        int q = t2 / NBpad;
        if (q >= 11) return;
        int idx = t2 - q * NBpad;
        if (idx >= NB) return;
        int g, m;
        if (q < 2)      { g = 0; m = q ? 10 : 0; }
        else if (q < 4) { g = 1; m = (q == 2) ? 1 : 9; }
        else if (q < 8) { g = 2; m = 2 + (q - 4); }
        else            { g = 3; m = 6 + (q - 8); }
        int bb = __builtin_amdgcn_readfirstlane(g);
        int dn = idx * 11 + m;
        const float* Wa = W1 + bb * (IN_F * IN_C);
        const float* ba = b1 + bb * IN_C;
        #pragma unroll
        for (int c = 0; c < IN_C; ++c) h[c] = ba[c];
        const float4* xd = reinterpret_cast<const float4*>(x_dna + (size_t)dn * IN_C);
        #pragma unroll
        for (int kk = 0; kk < 8; ++kk) {
            float4 xv = xd[kk];
            float fs[4] = {xv.x, xv.y, xv.z, xv.w};
            #pragma unroll
            for (int j = 0; j < 4; ++j)
                #pragma unroll
                for (int c = 0; c < IN_C; ++c)
                    h[c] = fmaf(fs[j], Wa[(36 + kk * 4 + j) * IN_C + c], h[c]);
        }
        unsigned yw[16];
        #pragma unroll
        for (int j = 0; j < 16; ++j)
            yw[j] = bf16r(h[2 * j]) | (bf16r(h[2 * j + 1]) << 16);
        uint4* d4 = reinterpret_cast<uint4*>(yd + (size_t)dn * IN_C);
        d4[0] = make_uint4(yw[0], yw[1], yw[2], yw[3]);
        d4[1] = make_uint4(yw[4], yw[5], yw[6], yw[7]);
        d4[2] = make_uint4(yw[8], yw[9], yw[10], yw[11]);
        d4[3] = make_uint4(yw[12], yw[13], yw[14], yw[15]);
    }
}

// ======================= FAST-PATH CSR BUILD =================================
__global__ __launch_bounds__(256) void k_passA(
    const int* __restrict__ esrc, const int* __restrict__ edst, int E,
    int nbkt, int* __restrict__ gcur, unsigned* __restrict__ stage)
{
    __shared__ unsigned rec[TILE_A];
    __shared__ unsigned short bkt[TILE_A];
    __shared__ int hist[NBKT_MAX];
    __shared__ int hscan[NBKT_MAX];
    __shared__ int cnt[NBKT_MAX];
    __shared__ int gpos[NBKT_MAX];
    __shared__ int chbase[8];

    int base = blockIdx.x * TILE_A;
    int n = E - base; if (n > TILE_A) n = TILE_A;
    if (n <= 0) return;

    for (int i = threadIdx.x; i < nbkt; i += 256) hist[i] = 0;
    __syncthreads();

    unsigned myrec[16];
    int mybkt[16];
    #pragma unroll
    for (int k = 0; k < 16; ++k) {
        int i = threadIdx.x + k * 256;
        mybkt[k] = -1;
        if (i < n) {
            int s = esrc[base + i];
            int d = edst[base + i];
            int b = d >> BK_SHIFT;
            myrec[k] = ((unsigned)(d & ((1 << BK_SHIFT) - 1)) << 17) | (unsigned)s;
            mybkt[k] = b;
            atomicAdd(&hist[b], 1);
        }
    }
    __syncthreads();

    {
        int lane = threadIdx.x & 63, w = threadIdx.x >> 6;
        int nch = (nbkt + 63) >> 6;
        for (int ch = w; ch < nch; ch += 4) {
            int idx = (ch << 6) + lane;
            int v = (idx < nbkt) ? hist[idx] : 0;
            int inc = v;
            #pragma unroll
            for (int d = 1; d < 64; d <<= 1) {
                int u = __shfl_up(inc, d, 64);
                if (lane >= d) inc += u;
            }
            if (idx < nbkt) hscan[idx] = inc - v;
            if (lane == 63) chbase[ch] = inc;
        }
        __syncthreads();
        if (threadIdx.x == 0) {
            int s = 0;
            for (int ch = 0; ch < nch; ++ch) { int t2 = chbase[ch]; chbase[ch] = s; s += t2; }
        }
        __syncthreads();
        for (int i = threadIdx.x; i < nbkt; i += 256) {
            int v = hscan[i] + chbase[i >> 6];
            hscan[i] = v;
            cnt[i] = v;
        }
    }
    // reserve: gcur holds pure counts (zero-init); absolute pos = b*BCAP + old
    for (int b2 = threadIdx.x; b2 < nbkt; b2 += 256) {
        int c = hist[b2];
        if (c > 0) gpos[b2] = b2 * BCAP + atomicAdd(&gcur[b2], c);
    }
    __syncthreads();

    #pragma unroll
    for (int k = 0; k < 16; ++k) {
        if (mybkt[k] >= 0) {
            int p = atomicAdd(&cnt[mybkt[k]], 1);
            rec[p] = myrec[k];
            bkt[p] = (unsigned short)mybkt[k];
        }
    }
    __syncthreads();

    for (int i = threadIdx.x; i < n; i += 256) {
        int b2 = bkt[i];
        stage[gpos[b2] + (i - hscan[b2])] = rec[i];
    }
}

// per-bucket: local pstart (reduce gcur[0..b)), CSR + histogram in LDS
__global__ __launch_bounds__(256) void k_passB2(
    const unsigned* __restrict__ stage, const int* __restrict__ gcur,
    int nbkt, int ND,
    int* __restrict__ counts, int* __restrict__ rowend,
    int* __restrict__ pool_src, int* __restrict__ hist)
{
    __shared__ int lcnt[512];
    __shared__ int lpre[512];
    __shared__ int lh[256];
    __shared__ int wsum[4];
    __shared__ int spp[4];
    __shared__ int s_pstart;

    int b = blockIdx.x;

    // pstart = sum of bucket counts below b (block reduce over gcur)
    {
        int partial = 0;
        for (int i = threadIdx.x; i < b; i += 256) partial += gcur[i];
        #pragma unroll
        for (int d = 1; d < 64; d <<= 1) partial += __shfl_xor(partial, d, 64);
        int lane = threadIdx.x & 63, w = threadIdx.x >> 6;
        if (lane == 0) spp[w] = partial;
    }
    lcnt[threadIdx.x] = 0;
    lcnt[threadIdx.x + 256] = 0;
    lh[threadIdx.x] = 0;
    __syncthreads();
    if (threadIdx.x == 0) s_pstart = spp[0] + spp[1] + spp[2] + spp[3];
    __syncthreads();

    int cnt = gcur[b];
    int pstart = s_pstart;
    int dbase = b << BK_SHIFT;

    for (int i = threadIdx.x; i < cnt; i += 256)
        atomicAdd(&lcnt[stage[(size_t)b * BCAP + i] >> 17], 1);
    __syncthreads();

    int e0 = lcnt[2 * threadIdx.x], e1 = lcnt[2 * threadIdx.x + 1];
    int s = e0 + e1;
    int lane = threadIdx.x & 63, w = threadIdx.x >> 6;
    int inc = s;
    #pragma unroll
    for (int d = 1; d < 64; d <<= 1) {
        int u = __shfl_up(inc, d, 64);
        if (lane >= d) inc += u;
    }
    if (lane == 63) wsum[w] = inc;
    __syncthreads();
    if (threadIdx.x == 0) {
        int a = 0;
        #pragma unroll
        for (int g = 0; g < 4; ++g) { int tmp = wsum[g]; wsum[g] = a; a += tmp; }
    }
    __syncthreads();
    int excl = inc - s + wsum[w];
    lpre[2 * threadIdx.x]     = excl;
    lpre[2 * threadIdx.x + 1] = excl + e0;

    #pragma unroll
    for (int k = 0; k < 2; ++k) {
        int nid = 2 * threadIdx.x + k;
        int node = dbase + nid;
        if (node < ND) {
            int c = lcnt[nid];
            counts[node] = c;
            rowend[node] = pstart + lpre[nid] + c;
            int cc = c > 63 ? 63 : c;
            atomicAdd(&lh[branch_of(node % 11) * 64 + (63 - cc)], 1);
        }
    }
    __syncthreads();
    if (lh[threadIdx.x]) atomicAdd(&hist[threadIdx.x], lh[threadIdx.x]);

    for (int i = threadIdx.x; i < cnt; i += 256) {
        unsigned r = stage[(size_t)b * BCAP + i];
        int nid = r >> 17;
        int pos = atomicAdd(&lpre[nid], 1);
        pool_src[pstart + pos] = (int)(r & 0x1FFFFu);
    }
}

// fused tail: blocks [0,nbA) = assign (local padscan + global cur ranks);
//             blocks [nbA,..) = precompute. Block 0 writes pbs + pad holes.
__global__ __launch_bounds__(256) void k_tail(
    const int* __restrict__ counts, const int* __restrict__ hist,
    int* __restrict__ cur, int* __restrict__ pbs,
    int* __restrict__ node_order, int ND, int nbA,
    const float* __restrict__ x_prot, const float* __restrict__ x_dna,
    const float* __restrict__ v_prot, const float* __restrict__ prot_vec,
    const float* __restrict__ W1, const float* __restrict__ b1,
    int NP, int NPpad, int NB, int NBpad,
    unsigned* __restrict__ yrec, unsigned short* __restrict__ yd)
{
    if ((int)blockIdx.x >= nbA) {
        int t = (blockIdx.x - nbA) * 256 + threadIdx.x;
        precomp_body(t, x_prot, x_dna, v_prot, prot_vec, W1, b1,
                     NP, NPpad, NB, NBpad, 1, 1, yrec, nullptr, yd);
        return;
    }

    __shared__ int sh_scan[256];
    __shared__ int sh_gb[5];
    __shared__ int sh_ge[4];
    __shared__ int gsum[4];

    int lane = threadIdx.x & 63;
    int w = threadIdx.x >> 6;
    int v = hist[threadIdx.x];
    int inc = v;
    #pragma unroll
    for (int d = 1; d < 64; d <<= 1) {
        int u = __shfl_up(inc, d, 64);
        if (lane >= d) inc += u;
    }
    if (lane == 63) gsum[w] = inc;
    __syncthreads();
    if (threadIdx.x == 0) {
        int base = 0;
        #pragma unroll
        for (int g = 0; g < 4; ++g) {
            sh_gb[g] = base;
            sh_ge[g] = base + gsum[g];
            base = (base + gsum[g] + 31) & ~31;   // 32-node aligned group base
        }
        sh_gb[4] = base;
    }
    __syncthreads();
    sh_scan[threadIdx.x] = sh_gb[w] + inc - v;
    __syncthreads();

    int t = blockIdx.x * 256 + threadIdx.x;
    if (t < ND) {
        int g = branch_of(t % 11);
        int c = counts[t]; c = c > 63 ? 63 : c;
        int bin = g * 64 + (63 - c);
        int rank = atomicAdd(&cur[bin], 1);
        node_order[sh_scan[bin] + rank] = t;
    }

    if (blockIdx.x == 0) {
        if (threadIdx.x < 5) pbs[threadIdx.x] = sh_gb[threadIdx.x];
        if (threadIdx.x < 128) {
            int g = threadIdx.x >> 5, k = threadIdx.x & 31;
            int pos = sh_ge[g] + k;
            if (pos < sh_gb[g + 1]) node_order[pos] = -1;  // pad holes
        }
    }
}

// ======================= LEGACY CSR BUILD (fallback) =========================
__global__ void k_count(const int* __restrict__ edst, int E, int* counts) {
    int t = blockIdx.x * blockDim.x + threadIdx.x;
    if (t >= E) return;
    atomicAdd(&counts[edst[t]], 1);
}

__global__ __launch_bounds__(1024) void k_scan1(const int* __restrict__ counts,
                                                int NN, int NDp, int* cursor,
                                                int* blk, int* hist,
                                                int* node_order) {
    __shared__ int wsum[16];
    __shared__ int lh[256];
    if (threadIdx.x < 256) lh[threadIdx.x] = 0;
    __syncthreads();
    int t = blockIdx.x * 1024 + threadIdx.x;
    int lane = threadIdx.x & 63;
    int wid = threadIdx.x >> 6;
    int c = (t < NN) ? counts[t] : 0;
    if (t < NN) {
        int g = branch_of(t % 11);
        int cc = c > 63 ? 63 : c;
        atomicAdd(&lh[g * 64 + (63 - cc)], 1);
    }
    if (t < NDp) node_order[t] = -1;
    int inc = c;
    #pragma unroll
    for (int d = 1; d < 64; d <<= 1) {
        int v = __shfl_up(inc, d, 64);
        if (lane >= d) inc += v;
    }
    if (lane == 63) wsum[wid] = inc;
    __syncthreads();
    if (threadIdx.x < 16) {
        int v = wsum[threadIdx.x];
        int wi = v;
        #pragma unroll
        for (int d = 1; d < 16; d <<= 1) {
            int u = __shfl_up(wi, d, 64);
            if (threadIdx.x >= d) wi += u;
        }
        wsum[threadIdx.x] = wi - v;
        if (threadIdx.x == 15) blk[blockIdx.x] = wi;
    }
    __syncthreads();
    if (t < NN) cursor[t] = inc - c + wsum[wid];
    if (threadIdx.x < 256 && lh[threadIdx.x])
        atomicAdd(&hist[threadIdx.x], lh[threadIdx.x]);
}

__global__ __launch_bounds__(256) void k_scan2(int* blk, int nblk) {
    __shared__ int wsum[4];
    int lane = threadIdx.x & 63;
    int wid = threadIdx.x >> 6;
    int v = (threadIdx.x < nblk) ? blk[threadIdx.x] : 0;
    int inc = v;
    #pragma unroll
    for (int d = 1; d < 64; d <<= 1) {
        int u = __shfl_up(inc, d, 64);
        if (lane >= d) inc += u;
    }
    if (lane == 63) wsum[wid] = inc;
    __syncthreads();
    if (threadIdx.x < 4) {
        int w = wsum[threadIdx.x];
        int wi = w;
        #pragma unroll
        for (int d = 1; d < 4; d <<= 1) {
            int u = __shfl_up(wi, d, 64);
            if (threadIdx.x >= d) wi += u;
        }
        wsum[threadIdx.x] = wi - w;
    }
    __syncthreads();
    if (threadIdx.x < nblk) blk[threadIdx.x] = inc - v + wsum[wid];
}

__global__ __launch_bounds__(1024) void k_scan3(int* cursor, const int* blk, int NN) {
    int t = blockIdx.x * 1024 + threadIdx.x;
    if (t >= NN) return;
    cursor[t] += blk[blockIdx.x];
}

__global__ void k_fill(const int* __restrict__ esrc, const int* __restrict__ edst,
                       int E, int* cursor, int* __restrict__ pool_src) {
    int t = blockIdx.x * blockDim.x + threadIdx.x;
    if (t >= E) return;
    int pos = atomicAdd(&cursor[edst[t]], 1);
    pool_src[pos] = esrc[t];
}

__global__ __launch_bounds__(256) void k_padscan2(int* hist, int* pbs) {
    __shared__ int gsum[4];
    __shared__ int gbase[5];
    int lane = threadIdx.x & 63;
    int w = threadIdx.x >> 6;
    int v = hist[threadIdx.x];
    int inc = v;
    #pragma unroll
    for (int d = 1; d < 64; d <<= 1) {
        int u = __shfl_up(inc, d, 64);
        if (lane >= d) inc += u;
    }
    if (lane == 63) gsum[w] = inc;
    __syncthreads();
    if (threadIdx.x == 0) {
        int base = 0;
        #pragma unroll
        for (int g = 0; g < 4; ++g) {
            gbase[g] = base;
            base = (base + gsum[g] + 31) & ~31;
        }
        gbase[4] = base;
    }
    __syncthreads();
    hist[threadIdx.x] = gbase[w] + inc - v;
    if (threadIdx.x < 5) pbs[threadIdx.x] = gbase[threadIdx.x];
}

__global__ __launch_bounds__(256) void k_assign(const int* __restrict__ counts,
                                                int ND, int* cur,
                                                int* __restrict__ node_order) {
    __shared__ int lh[256];
    __shared__ int lbase[256];
    lh[threadIdx.x] = 0;
    __syncthreads();
    int t = blockIdx.x * 256 + threadIdx.x;
    bool v = (t < ND);
    int bin = 0, rank = 0;
    if (v) {
        int g = branch_of(t % 11);
        int c = counts[t]; c = c > 63 ? 63 : c;
        bin = g * 64 + (63 - c);
        rank = atomicAdd(&lh[bin], 1);
    }
    __syncthreads();
    int cnt = lh[threadIdx.x];
    if (cnt > 0) lbase[threadIdx.x] = atomicAdd(&cur[threadIdx.x], cnt);
    __syncthreads();
    if (v) node_order[lbase[bin] + rank] = t;
}

__global__ __launch_bounds__(256) void k_precomp(
    const float* __restrict__ x_prot, const float* __restrict__ x_dna,
    const float* __restrict__ v_prot, const float* __restrict__ prot_vec,
    const float* __restrict__ W1, const float* __restrict__ b1,
    int NP, int NPpad, int NB, int NBpad, int do_dna, int fp8mode,
    unsigned* __restrict__ yrec, unsigned short* __restrict__ ypb,
    unsigned short* __restrict__ yd)
{
    int t = blockIdx.x * 256 + threadIdx.x;
    precomp_body(t, x_prot, x_dna, v_prot, prot_vec, W1, b1,
                 NP, NPpad, NB, NBpad, do_dna, fp8mode, yrec, ypb, yd);
}

// ======================= MFMA MAIN ===========================================
__global__ __launch_bounds__(256) void k_mfma(
    const float* __restrict__ v_dna, const float* __restrict__ dna_vec,
    const float* __restrict__ W1, const float* __restrict__ W2,
    const float* __restrict__ b2,
    const int* __restrict__ node_order, const int* __restrict__ rowend,
    const int* __restrict__ counts, const int* __restrict__ pool_src,
    const int* __restrict__ pbs,
    const unsigned* __restrict__ yrec, const unsigned short* __restrict__ yd,
    int NP, float* __restrict__ out, float* __restrict__ conv, int NDp)
{
    // bijective XCD swizzle: contiguous logical range per XCD
    int nblk = gridDim.x;
    int q8 = nblk >> 3, r8 = nblk & 7;
    int x = blockIdx.x & 7, bidx = blockIdx.x >> 3;
    int lb = (x < r8 ? x * (q8 + 1) : r8 * (q8 + 1) + (x - r8) * q8) + bidx;

    int t = lb * 256 + threadIdx.x;
    int lane = threadIdx.x & 63;
    int hi = lane >> 5;
    int col = lane & 31;
    int pid = t >> 1;
    int sub = t & 1;

    int pb1 = pbs[1], pb2v = pbs[2], pb3 = pbs[3], pb4 = pbs[4];
    int g = (pid >= pb1) + (pid >= pb2v) + (pid >= pb3);
    int bb = __builtin_amdgcn_readfirstlane(g);

    int dst = (pid < pb4) ? node_order[pid] : -1;   // pb4 32-aligned: wave-safe
    bool vnode = (dst >= 0);
    int dsafe = vnode ? dst : 0;
    int n_all = vnode ? counts[dsafe] : 0;
    int start = vnode ? (rowend[dsafe] - n_all) : 0;

    const float* Wp = W1 + bb * (IN_F * IN_C) + 32 * IN_C;
    const float* Wb = W2 + bb * (IN_C * IN_C);
    float b2c = b2[bb * IN_C + col];

    U4F B0u, B1u;
    #pragma unroll
    for (int j = 0; j < 4; ++j) {
        int k0 = hi * 8 + 2 * j;
        B0u.u[j] = cvtpk_bf16(Wb[k0 * IN_C + col],        Wb[(k0 + 1) * IN_C + col]);
        B1u.u[j] = cvtpk_bf16(Wb[(16 + k0) * IN_C + col], Wb[(17 + k0) * IN_C + col]);
    }

    float vdx = v_dna[dsafe * 3 + 0], vdy = v_dna[dsafe * 3 + 1], vdz = v_dna[dsafe * 3 + 2];
    float nix = dna_vec[dsafe * 3 + 0], niy = dna_vec[dsafe * 3 + 1], niz = dna_vec[dsafe * 3 + 2];

    unsigned ydw[16];
    {
        const uint4* ydv = reinterpret_cast<const uint4*>(yd + (size_t)dsafe * IN_C);
        uint4 w0 = ydv[0], w1 = ydv[1], w2 = ydv[2], w3 = ydv[3];
        *reinterpret_cast<uint4*>(&ydw[0])  = w0;
        *reinterpret_cast<uint4*>(&ydw[4])  = w1;
        *reinterpret_cast<uint4*>(&ydw[8])  = w2;
        *reinterpret_cast<uint4*>(&ydw[12]) = w3;
    }

    float acc[16];
    #pragma unroll
    for (int i = 0; i < 16; ++i) acc[i] = 0.0f;

    int niter = (n_all + 1) >> 1;
    #pragma unroll
    for (int d = 1; d < 64; d <<= 1) {
        int o = __shfl_xor(niter, d, 64);
        niter = niter > o ? niter : o;
    }

    // software pipeline: prefetch pool + merged record one iteration ahead
    unsigned ywc[8];
    unsigned gwc[4];
    if (niter > 0) {
        bool v0 = vnode && (sub < n_all);
        int off0 = v0 ? (start + sub) : 0;
        int src0 = pool_src[off0];
        const uint4* yv = reinterpret_cast<const uint4*>(yrec + ((size_t)bb * NP + src0) * 16);
        uint4 y0 = yv[0], y1 = yv[1], g2 = yv[2];
        *reinterpret_cast<uint4*>(&ywc[0]) = y0;
        *reinterpret_cast<uint4*>(&ywc[4]) = y1;
        *reinterpret_cast<uint4*>(&gwc[0]) = g2;
    }

    for (int it = 0; it < niter; ++it) {
        bool valid = vnode && (2 * it + sub < n_all);
        unsigned long long vm = __ballot(valid);

        // prefetch next iteration
        int it1 = it + 1;
        bool vn = (it1 < niter) && vnode && (2 * it1 + sub < n_all);
        int offn = vn ? (start + 2 * it1 + sub) : 0;
        int src_n = pool_src[offn];
        const uint4* yvn = reinterpret_cast<const uint4*>(yrec + ((size_t)bb * NP + src_n) * 16);
        uint4 n0 = yvn[0], n1 = yvn[1], n2 = yvn[2];

        // decode current geometry (bf16)
        float vpx = bflo(gwc[0]), vpy = bfhi(gwc[0]);
        float vpz = bflo(gwc[1]), njx = bfhi(gwc[1]);
        float njy = bflo(gwc[2]), njz = bfhi(gwc[2]);
        float dx = vpx - vdx, dy = vpy - vdy, dz = vpz - vdz;
        float pf0 = sqrtf(dx * dx + dy * dy + dz * dz);
        float pf1 = angf(nix, niy, niz, dx, dy, dz);
        float pf2 = angf(njx, njy, njz, dx, dy, dz);
        float pf3 = angf(nix, niy, niz, njx, njy, njz);

        // h1 = yd + yp(fp8) + Wp.ppf, relu, pack bf16 -> p[16]
        unsigned p[16];
        #pragma unroll
        for (int jj = 0; jj < 8; ++jj) {
            f32x2v f01 = __builtin_amdgcn_cvt_pk_f32_fp8((int)ywc[jj], false);
            f32x2v f23 = __builtin_amdgcn_cvt_pk_f32_fp8((int)ywc[jj], true);
            int c0 = 4 * jj;
            float a0 = bflo(ydw[2 * jj])     + f01[0];
            float a1 = bfhi(ydw[2 * jj])     + f01[1];
            float a2 = bflo(ydw[2 * jj + 1]) + f23[0];
            float a3 = bfhi(ydw[2 * jj + 1]) + f23[1];
            a0 = fmaf(pf0, Wp[0 * IN_C + c0],     a0);
            a0 = fmaf(pf1, Wp[1 * IN_C + c0],     a0);
            a0 = fmaf(pf2, Wp[2 * IN_C + c0],     a0);
            a0 = fmaf(pf3, Wp[3 * IN_C + c0],     a0);
            a1 = fmaf(pf0, Wp[0 * IN_C + c0 + 1], a1);
            a1 = fmaf(pf1, Wp[1 * IN_C + c0 + 1], a1);
            a1 = fmaf(pf2, Wp[2 * IN_C + c0 + 1], a1);
            a1 = fmaf(pf3, Wp[3 * IN_C + c0 + 1], a1);
            a2 = fmaf(pf0, Wp[0 * IN_C + c0 + 2], a2);
            a2 = fmaf(pf1, Wp[1 * IN_C + c0 + 2], a2);
            a2 = fmaf(pf2, Wp[2 * IN_C + c0 + 2], a2);
            a2 = fmaf(pf3, Wp[3 * IN_C + c0 + 2], a2);
            a3 = fmaf(pf0, Wp[0 * IN_C + c0 + 3], a3);
            a3 = fmaf(pf1, Wp[1 * IN_C + c0 + 3], a3);
            a3 = fmaf(pf2, Wp[2 * IN_C + c0 + 3], a3);
            a3 = fmaf(pf3, Wp[3 * IN_C + c0 + 3], a3);
            p[2 * jj]     = cvtpk_bf16(fmaxf(a0, 0.0f), fmaxf(a1, 0.0f));
            p[2 * jj + 1] = cvtpk_bf16(fmaxf(a2, 0.0f), fmaxf(a3, 0.0f));
        }

        unsigned q[16];
        #pragma unroll
        for (int j = 0; j < 16; ++j)
            q[j] = (unsigned)__shfl_xor((int)p[j], 32, 64);

        U4F a00, a01, a10, a11;
        #pragma unroll
        for (int d2 = 0; d2 < 4; ++d2) {
            a00.u[d2] = hi ? q[4 + d2]  : p[d2];
            a01.u[d2] = hi ? q[12 + d2] : p[8 + d2];
            a10.u[d2] = hi ? p[4 + d2]  : q[d2];
            a11.u[d2] = hi ? p[12 + d2] : q[8 + d2];
        }

        unsigned long long vms = vm >> (4 * hi);

        {
            f32x16v D;
            #pragma unroll
            for (int r = 0; r < 16; ++r) D[r] = 0.0f;
            D = __builtin_amdgcn_mfma_f32_32x32x16_bf16(a00.v, B0u.v, D, 0, 0, 0);
            D = __builtin_amdgcn_mfma_f32_32x32x16_bf16(a01.v, B1u.v, D, 0, 0, 0);
            #pragma unroll
            for (int r = 0; r < 16; ++r) {
                int sh = (r & 3) + 8 * (r >> 2);
                float val = fmaxf(D[r] + b2c, 0.0f);
                bool ok = (vms >> sh) & 1ull;
                int ai = 2 * (r >> 2) + ((r & 3) >> 1);
                acc[ai] += ok ? val : 0.0f;
            }
        }
        {
            f32x16v D;
            #pragma unroll
            for (int r = 0; r < 16; ++r) D[r] = 0.0f;
            D = __builtin_amdgcn_mfma_f32_32x32x16_bf16(a10.v, B0u.v, D, 0, 0, 0);
            D = __builtin_amdgcn_mfma_f32_32x32x16_bf16(a11.v, B1u.v, D, 0, 0, 0);
            #pragma unroll
            for (int r = 0; r < 16; ++r) {
                int sh = 32 + (r & 3) + 8 * (r >> 2);
                float val = fmaxf(D[r] + b2c, 0.0f);
                bool ok = (vms >> sh) & 1ull;
                int ai = 8 + 2 * (r >> 2) + ((r & 3) >> 1);
                acc[ai] += ok ? val : 0.0f;
            }
        }

        // rotate pipeline registers
        *reinterpret_cast<uint4*>(&ywc[0]) = n0;
        *reinterpret_cast<uint4*>(&ywc[4]) = n1;
        *reinterpret_cast<uint4*>(&gwc[0]) = n2;
    }

    #pragma unroll
    for (int i = 0; i < 16; ++i) {
        int rb = i >> 3, rem = i & 7;
        int q2 = rem >> 1, u = rem & 1;
        int m = 16 * rb + 4 * q2 + 2 * hi + u;
        int dm = __shfl(dst, 2 * m, 64);
        if (dm >= 0) {
            out[(size_t)dm * IN_C + col]  = acc[i];
            conv[(size_t)dm * IN_C + col] = acc[i];
        }
    }
}

// ======================= non-MFMA fallbacks ==================================
template <int MODE>
__global__ __launch_bounds__(256) void k_nodes4(
    const float* __restrict__ x_dna, const float* __restrict__ v_dna,
    const float* __restrict__ x_prot, const float* __restrict__ v_prot,
    const float* __restrict__ prot_vec, const float* __restrict__ dna_vec,
    const float* __restrict__ W1, const float* __restrict__ b1,
    const float* __restrict__ W2, const float* __restrict__ b2,
    const int* __restrict__ node_order, const int* __restrict__ rowend,
    const int* __restrict__ counts, const int* __restrict__ pool_src,
    const int* __restrict__ pbs,
    const unsigned short* __restrict__ yp,
    int NP, float* __restrict__ out, float* __restrict__ conv, int NDp)
{
    int t = blockIdx.x * 256 + threadIdx.x;
    int pid = t >> 2;
    int sub = t & 3;
    if (pid >= NDp) return;

    int pb1 = pbs[1], pb2 = pbs[2], pb3 = pbs[3];
    int g = (pid >= pb1) + (pid >= pb2) + (pid >= pb3);
    int bb = __builtin_amdgcn_readfirstlane(g);

    int dst = node_order[pid];
    bool valid = (dst >= 0);
    int dsafe = valid ? dst : 0;

    int n_all = valid ? counts[dsafe] : 0;
    int start_all = valid ? (rowend[dsafe] - n_all) : 0;
    int nb4 = n_all >> 2, rem = n_all & 3;
    int n = nb4 + (sub < rem ? 1 : 0);
    int start = start_all + sub * nb4 + (sub < rem ? sub : rem);

    const float* Wa  = W1 + bb * (IN_F * IN_C);
    const float* Wp  = Wa + 32 * IN_C;
    const float* Wb  = W2 + bb * (IN_C * IN_C);
    const float* ba  = b1 + bb * IN_C;
    const float* bb2 = b2 + bb * IN_C;

    float vdx = v_dna[dsafe * 3 + 0], vdy = v_dna[dsafe * 3 + 1], vdz = v_dna[dsafe * 3 + 2];
    float nix = dna_vec[dsafe * 3 + 0], niy = dna_vec[dsafe * 3 + 1], niz = dna_vec[dsafe * 3 + 2];

    float h1b[IN_C];
    #pragma unroll
    for (int c = 0; c < IN_C; ++c) h1b[c] = ba[c];
    {
        const float4* xd = reinterpret_cast<const float4*>(x_dna + (size_t)dsafe * IN_C);
        #pragma unroll
        for (int kk = 0; kk < 8; ++kk) {
            float4 xv = xd[kk];
            float fs[4] = {xv.x, xv.y, xv.z, xv.w};
            #pragma unroll
            for (int j = 0; j < 4; ++j)
                #pragma unroll
                for (int c = 0; c < IN_C; ++c)
                    h1b[c] = fmaf(fs[j], Wa[(36 + kk * 4 + j) * IN_C + c], h1b[c]);
        }
    }

    float acc[IN_C];
    #pragma unroll
    for (int c = 0; c < IN_C; ++c) acc[c] = 0.0f;

    for (int k = 0; k < n; ++k) {
        int src = pool_src[start + k];
        float vpx = v_prot[src * 3 + 0], vpy = v_prot[src * 3 + 1], vpz = v_prot[src * 3 + 2];
        float njx = prot_vec[src * 3 + 0], njy = prot_vec[src * 3 + 1], njz = prot_vec[src * 3 + 2];
        float dx = vpx - vdx, dy = vpy - vdy, dz = vpz - vdz;
        float pf0 = sqrtf(dx * dx + dy * dy + dz * dz);
        float pf1 = angf(nix, niy, niz, dx, dy, dz);
        float pf2 = angf(njx, njy, njz, dx, dy, dz);
        float pf3 = angf(nix, niy, niz, njx, njy, njz);

        float h2[IN_C];
        #pragma unroll
        for (int c = 0; c < IN_C; ++c) h2[c] = bb2[c];

        if constexpr (MODE == 1) {
            unsigned yw[16];
            const uint4* ypv = reinterpret_cast<const uint4*>(yp + ((size_t)bb * NP + src) * IN_C);
            uint4 y0 = ypv[0], y1 = ypv[1], y2 = ypv[2], y3 = ypv[3];
            *reinterpret_cast<uint4*>(&yw[0])  = y0;
            *reinterpret_cast<uint4*>(&yw[4])  = y1;
            *reinterpret_cast<uint4*>(&yw[8])  = y2;
            *reinterpret_cast<uint4*>(&yw[12]) = y3;
            #pragma unroll
            for (int k2 = 0; k2 < IN_C; ++k2) {
                unsigned w = yw[k2 >> 1];
                float ypf = (k2 & 1) ? bfhi(w) : bflo(w);
                float h1v = h1b[k2] + ypf;
                h1v = fmaf(pf0, Wp[0 * IN_C + k2], h1v);
                h1v = fmaf(pf1, Wp[1 * IN_C + k2], h1v);
                h1v = fmaf(pf2, Wp[2 * IN_C + k2], h1v);
                h1v = fmaf(pf3, Wp[3 * IN_C + k2], h1v);
                float f = fmaxf(h1v, 0.0f);
                #pragma unroll
                for (int c = 0; c < IN_C; ++c)
                    h2[c] = fmaf(f, Wb[k2 * IN_C + c], h2[c]);
            }
        } else {
            float pf[4] = {pf0, pf1, pf2, pf3};
            const float4* xp = reinterpret_cast<const float4*>(x_prot + (size_t)src * IN_C);
            #pragma unroll
            for (int hh = 0; hh < 2; ++hh) {
                float h1h[16];
                #pragma unroll
                for (int c = 0; c < 16; ++c) h1h[c] = h1b[hh * 16 + c];
                #pragma unroll
                for (int kk = 0; kk < 8; ++kk) {
                    float4 xv = xp[kk];
                    float fs[4] = {xv.x, xv.y, xv.z, xv.w};
                    #pragma unroll
                    for (int j = 0; j < 4; ++j)
                        #pragma unroll
                        for (int c = 0; c < 16; ++c)
                            h1h[c] = fmaf(fs[j], Wa[(kk * 4 + j) * IN_C + hh * 16 + c], h1h[c]);
                }
                #pragma unroll
                for (int j = 0; j < 4; ++j)
                    #pragma unroll
                    for (int c = 0; c < 16; ++c)
                        h1h[c] = fmaf(pf[j], Wp[j * IN_C + hh * 16 + c], h1h[c]);
                #pragma unroll
                for (int k2 = 0; k2 < 16; ++k2) {
                    float f = fmaxf(h1h[k2], 0.0f);
                    #pragma unroll
                    for (int c = 0; c < IN_C; ++c)
                        h2[c] = fmaf(f, Wb[(hh * 16 + k2) * IN_C + c], h2[c]);
                }
            }
        }

        #pragma unroll
        for (int c = 0; c < IN_C; ++c)
            acc[c] += fmaxf(h2[c], 0.0f);
    }

    #pragma unroll
    for (int c = 0; c < IN_C; ++c)
        acc[c] += __shfl_xor(acc[c], 1, 64);
    #pragma unroll
    for (int c = 0; c < IN_C; ++c)
        acc[c] += __shfl_xor(acc[c], 2, 64);

    if (valid && sub < 2) {
        float* p = (sub ? conv : out) + (size_t)dst * IN_C;
        float4* p4 = reinterpret_cast<float4*>(p);
        #pragma unroll
        for (int qq = 0; qq < 8; ++qq) {
            float4 v;
            v.x = acc[qq * 4 + 0]; v.y = acc[qq * 4 + 1];
            v.z = acc[qq * 4 + 2]; v.w = acc[qq * 4 + 3];
            p4[qq] = v;
        }
    }
}

__global__ __launch_bounds__(256) void k_edges_fallback(
    const float* __restrict__ x_dna, const float* __restrict__ v_dna,
    const float* __restrict__ x_prot, const float* __restrict__ v_prot,
    const float* __restrict__ prot_vec, const float* __restrict__ dna_vec,
    const int* __restrict__ esrc, const int* __restrict__ edst,
    const float* __restrict__ W1, const float* __restrict__ b1,
    const float* __restrict__ W2, const float* __restrict__ b2,
    int E, float* __restrict__ conv)
{
    int t = blockIdx.x * blockDim.x + threadIdx.x;
    if (t >= E) return;
    int src = esrc[t], dst = edst[t];
    int b = branch_of(dst % 11);
    const float* Wa  = W1 + b * (IN_F * IN_C);
    const float* Wb  = W2 + b * (IN_C * IN_C);
    const float* ba  = b1 + b * IN_C;
    const float* bb2 = b2 + b * IN_C;

    float vdx = v_dna[dst * 3 + 0], vdy = v_dna[dst * 3 + 1], vdz = v_dna[dst * 3 + 2];
    float vpx = v_prot[src * 3 + 0], vpy = v_prot[src * 3 + 1], vpz = v_prot[src * 3 + 2];
    float nix = dna_vec[dst * 3 + 0], niy = dna_vec[dst * 3 + 1], niz = dna_vec[dst * 3 + 2];
    float njx = prot_vec[src * 3 + 0], njy = prot_vec[src * 3 + 1], njz = prot_vec[src * 3 + 2];
    float dx = vpx - vdx, dy = vpy - vdy, dz = vpz - vdz;
    float pf[4];
    pf[0] = sqrtf(dx * dx + dy * dy + dz * dz);
    pf[1] = angf(nix, niy, niz, dx, dy, dz);
    pf[2] = angf(njx, njy, njz, dx, dy, dz);
    pf[3] = angf(nix, niy, niz, njx, njy, njz);

    float h1[IN_C];
    #pragma unroll
    for (int c = 0; c < IN_C; ++c) h1[c] = ba[c];
    const float4* xp = reinterpret_cast<const float4*>(x_prot + (size_t)src * IN_C);
    #pragma unroll
    for (int kk = 0; kk < 8; ++kk) {
        float4 xv = xp[kk];
        float fs[4] = {xv.x, xv.y, xv.z, xv.w};
        #pragma unroll
        for (int j = 0; j < 4; ++j)
            #pragma unroll
            for (int c = 0; c < IN_C; ++c)
                h1[c] = fmaf(fs[j], Wa[(kk * 4 + j) * IN_C + c], h1[c]);
    }
    #pragma unroll
    for (int j = 0; j < 4; ++j)
        #pragma unroll
        for (int c = 0; c < IN_C; ++c)
            h1[c] = fmaf(pf[j], Wa[(32 + j) * IN_C + c], h1[c]);
    const float4* xd = reinterpret_cast<const float4*>(x_dna + (size_t)dst * IN_C);
    #pragma unroll
    for (int kk = 0; kk < 8; ++kk) {
        float4 xv = xd[kk];
        float fs[4] = {xv.x, xv.y, xv.z, xv.w};
        #pragma unroll
        for (int j = 0; j < 4; ++j)
            #pragma unroll
            for (int c = 0; c < IN_C; ++c)
                h1[c] = fmaf(fs[j], Wa[(36 + kk * 4 + j) * IN_C + c], h1[c]);
    }
    float h2[IN_C];
    #pragma unroll
    for (int c = 0; c < IN_C; ++c) h2[c] = bb2[c];
    #pragma unroll
    for (int k = 0; k < IN_C; ++k) {
        float f = fmaxf(h1[k], 0.0f);
        #pragma unroll
        for (int c = 0; c < IN_C; ++c)
            h2[c] = fmaf(f, Wb[k * IN_C + c], h2[c]);
    }
    float* cv = conv + (size_t)dst * IN_C;
    #pragma unroll
    for (int c = 0; c < IN_C; ++c)
        atomicAdd(&cv[c], fmaxf(h2[c], 0.0f));
}

extern "C" void kernel_launch(void* const* d_in, const int* in_sizes, int n_in,
                              void* d_out, int out_size, void* d_ws, size_t ws_size,
                              hipStream_t stream) {
    const float* x_dna    = (const float*)d_in[0];
    const float* v_dna    = (const float*)d_in[1];
    const float* x_prot   = (const float*)d_in[2];
    const float* v_prot   = (const float*)d_in[3];
    const float* prot_vec = (const float*)d_in[4];
    const float* dna_vec  = (const float*)d_in[5];
    const int*   esrc     = (const int*)d_in[6];
    const int*   edst     = (const int*)d_in[7];
    const float* W1       = (const float*)d_in[8];
    const float* b1       = (const float*)d_in[9];
    const float* W2       = (const float*)d_in[10];
    const float* b2       = (const float*)d_in[11];

    const int E  = in_sizes[6];
    const int ND = in_sizes[0] / IN_C;       // N_DNA
    const int NP = in_sizes[2] / IN_C;       // N_PROT
    const int half = out_size / 2;
    float* out  = (float*)d_out;
    float* conv = out + half;

    const int NDp = (ND + 160 + 31) & ~31;
    const int nblk_scan = (NDp + 1023) / 1024;
    const int eb = (E + 255) / 256;

    // ws: counts | hist(256) | gcur(512) | cur(256) | pbs(16) | blk(256)
    //     | rowcur | node_order | pool | yrec | yd
    const size_t base_ints = (size_t)ND + 256 + 512 + 256 + 16 + 256 + ND + NDp + E;
    const size_t ws_base   = base_ints * sizeof(int);
    const size_t yp_off    = (ws_base + 255) & ~(size_t)255;
    const size_t yrec_bytes = (size_t)NP * 4 * 64;                  // 64B/record
    const size_t ypb_bytes  = (size_t)NP * 4 * IN_C * 2;            // bf16 legacy
    const size_t yd_off    = yp_off + yrec_bytes;
    const size_t yd_bytes  = (size_t)ND * IN_C * sizeof(unsigned short);

    if (ND == half / IN_C && ws_size >= ws_base && nblk_scan <= 256) {
        int* counts     = (int*)d_ws;          // ND
        int* hist       = counts + ND;         // 256
        int* gcur       = hist + 256;          // 512
        int* cur        = gcur + 512;          // 256
        int* pbs        = cur + 256;           // 16
        int* blk        = pbs + 16;            // 256 (legacy)
        int* rowcur     = blk + 256;           // ND  (rowend in fast path)
        int* node_order = rowcur + ND;         // NDp
        int* pool_src   = node_order + NDp;    // E
        unsigned*       yrec = (unsigned*)((char*)d_ws + yp_off);
        unsigned short* ypb  = (unsigned short*)((char*)d_ws + yp_off);  // legacy alias
        unsigned short* yd   = (unsigned short*)((char*)d_ws + yd_off);

        int mode = 0;
        if (ws_size >= yd_off + yd_bytes && ND % 11 == 0) mode = 2;
        else if (ws_size >= yp_off + ypb_bytes)           mode = 1;

        const int nbkt = (ND + (1 << BK_SHIFT) - 1) >> BK_SHIFT;
        const size_t stage_bytes = (size_t)nbkt * BCAP * sizeof(unsigned);
        const bool fastfill = (mode == 2) && (NP < (1 << 17)) && (nbkt <= NBKT_MAX)
                              && (stage_bytes <= yrec_bytes)
                              && (E / nbkt + 512 < BCAP);

        int NPpad = (NP + 63) & ~63;
        int NB = ND / 11;
        int NBpad = (NB + 63) & ~63;

        if (fastfill) {
            unsigned* stage = yrec;   // overlay; dead after k_passB2
            // zero hist + gcur + cur (contiguous 1024 ints)
            hipMemsetAsync(hist, 0, 1024 * sizeof(int), stream);
            int na = (E + TILE_A - 1) / TILE_A;
            k_passA<<<na, 256, 0, stream>>>(esrc, edst, E, nbkt, gcur, stage);
            k_passB2<<<nbkt, 256, 0, stream>>>(stage, gcur, nbkt, ND,
                                               counts, rowcur, pool_src, hist);
            int nbA = (ND + 255) / 256;
            int totP = 4 * NPpad + 11 * NBpad;
            int nbP = (totP + 255) / 256;
            k_tail<<<nbA + nbP, 256, 0, stream>>>(
                counts, hist, cur, pbs, node_order, ND, nbA,
                x_prot, x_dna, v_prot, prot_vec, W1, b1,
                NP, NPpad, NB, NBpad, yrec, yd);
        } else {
            hipMemsetAsync(counts, 0, ((size_t)ND + 256) * sizeof(int), stream);
            k_count<<<eb, 256, 0, stream>>>(edst, E, counts);
            k_scan1<<<nblk_scan, 1024, 0, stream>>>(counts, ND, NDp, rowcur, blk,
                                                    hist, node_order);
            k_scan2<<<1, 256, 0, stream>>>(blk, nblk_scan);
            k_scan3<<<nblk_scan, 1024, 0, stream>>>(rowcur, blk, ND);
            k_fill<<<eb, 256, 0, stream>>>(esrc, edst, E, rowcur, pool_src);
            k_padscan2<<<1, 256, 0, stream>>>(hist, pbs);
            k_assign<<<(ND + 255) / 256, 256, 0, stream>>>(counts, ND, hist,
                                                           node_order);
            if (mode >= 1) {
                int tot = 4 * NPpad + (mode == 2 ? 11 * NBpad : 0);
                k_precomp<<<(tot + 255) / 256, 256, 0, stream>>>(
                    x_prot, x_dna, v_prot, prot_vec, W1, b1,
                    NP, NPpad, NB, NBpad, mode == 2, mode == 2,
                    yrec, ypb, yd);
            }
        }

        if (mode == 2) {
            int nbm = (2 * NDp + 255) / 256;
            k_mfma<<<nbm, 256, 0, stream>>>(
                v_dna, dna_vec, W1, W2, b2,
                node_order, rowcur, counts, pool_src, pbs,
                yrec, yd, NP, out, conv, NDp);
        } else if (mode == 1) {
            int nb4 = (4 * NDp + 255) / 256;
            k_nodes4<1><<<nb4, 256, 0, stream>>>(
                x_dna, v_dna, x_prot, v_prot, prot_vec, dna_vec,
                W1, b1, W2, b2, node_order, rowcur, counts, pool_src, pbs,
                ypb, NP, out, conv, NDp);
        } else {
            int nb4 = (4 * NDp + 255) / 256;
            k_nodes4<0><<<nb4, 256, 0, stream>>>(
                x_dna, v_dna, x_prot, v_prot, prot_vec, dna_vec,
                W1, b1, W2, b2, node_order, rowcur, counts, pool_src, pbs,
                nullptr, NP, out, conv, NDp);
        }
    } else {
        hipMemsetAsync(conv, 0, (size_t)half * sizeof(float), stream);
        k_edges_fallback<<<eb, 256, 0, stream>>>(
            x_dna, v_dna, x_prot, v_prot, prot_vec, dna_vec,
            esrc, edst, W1, b1, W2, b2, E, conv);
        hipMemcpyAsync(out, conv, (size_t)half * sizeof(float),
                       hipMemcpyDeviceToDevice, stream);
    }
}

// Round 15
// 173.202 us; speedup vs baseline: 2.6243x; 2.6243x over previous
//
#include <hip/hip_runtime.h>

// ---------------------------------------------------------------------------
// BiNet R15 = R14 with the k_tail assign bug fixed:
//   R14's fused assign did per-thread atomicAdd(&cur[bin]) -- 220K atomics
//   over 256 addresses = serialized L2 RMW storm (k_tail 338us, VALU 6%).
//   Fix: block-LDS-aggregated ranks (one global atomic per nonzero bin per
//   block), exactly R13's k_assign scheme, inside the fused kernel.
//   All R14 fusions kept: memset init, passB2 local pstart, fused precomp,
//   pb4-bounded k_mfma.
// ---------------------------------------------------------------------------

#define IN_C 32
#define IN_F 68
#define TILE_A 4096
#define BK_SHIFT 9
#define NBKT_MAX 448
#define BCAP 6144

using bf16x8v = __attribute__((ext_vector_type(8))) short;
using f32x16v = __attribute__((ext_vector_type(16))) float;
using f32x2v  = __attribute__((ext_vector_type(2))) float;

union U4F { unsigned u[4]; bf16x8v v; };

__device__ __forceinline__ unsigned cvtpk_bf16(float a, float b) {
    unsigned r;
    asm("v_cvt_pk_bf16_f32 %0, %1, %2" : "=v"(r) : "v"(a), "v"(b));
    return r;
}
__device__ __forceinline__ float bflo(unsigned u) { return __uint_as_float(u << 16); }
__device__ __forceinline__ float bfhi(unsigned u) { return __uint_as_float(u & 0xffff0000u); }

__device__ __forceinline__ float angf(float ax, float ay, float az,
                                      float bx, float by, float bz) {
    float cx = ay * bz - az * by;
    float cy = az * bx - ax * bz;
    float cz = ax * by - ay * bx;
    float cn = sqrtf(cx * cx + cy * cy + cz * cz);
    float dt = ax * bx + ay * by + az * bz;
    return atan2f(cn, dt);
}

__device__ __forceinline__ int branch_of(int m) {
    if (m == 0 || m == 10) return 0;
    if (m == 1 || m == 9)  return 1;
    if (m >= 2 && m <= 5)  return 2;
    return 3;
}

__device__ __forceinline__ unsigned bf16r(float f) {
    unsigned u = __float_as_uint(f);
    return (u + 0x7fffu + ((u >> 16) & 1u)) >> 16;
}

// ======================= shared precompute body ==============================
__device__ __forceinline__ void precomp_body(
    int t,
    const float* __restrict__ x_prot, const float* __restrict__ x_dna,
    const float* __restrict__ v_prot, const float* __restrict__ prot_vec,
    const float* __restrict__ W1, const float* __restrict__ b1,
    int NP, int NPpad, int NB, int NBpad, int do_dna, int fp8mode,
    unsigned* __restrict__ yrec, unsigned short* __restrict__ ypb,
    unsigned short* __restrict__ yd)
{
    int NP4 = 4 * NPpad;
    float h[IN_C];

    if (t < NP4) {
        int g = t / NPpad;
        int p = t - g * NPpad;
        if (p >= NP) return;
        int bb = __builtin_amdgcn_readfirstlane(g);
        const float* Wa = W1 + bb * (IN_F * IN_C);
        #pragma unroll
        for (int c = 0; c < IN_C; ++c) h[c] = 0.0f;
        const float4* xp = reinterpret_cast<const float4*>(x_prot + (size_t)p * IN_C);
        #pragma unroll
        for (int kk = 0; kk < 8; ++kk) {
            float4 xv = xp[kk];
            float fs[4] = {xv.x, xv.y, xv.z, xv.w};
            #pragma unroll
            for (int j = 0; j < 4; ++j)
                #pragma unroll
                for (int c = 0; c < IN_C; ++c)
                    h[c] = fmaf(fs[j], Wa[(kk * 4 + j) * IN_C + c], h[c]);
        }
        if (fp8mode) {
            unsigned yw[8];
            #pragma unroll
            for (int j = 0; j < 8; ++j) {
                int w = 0;
                w = __builtin_amdgcn_cvt_pk_fp8_f32(h[4 * j],     h[4 * j + 1], w, false);
                w = __builtin_amdgcn_cvt_pk_fp8_f32(h[4 * j + 2], h[4 * j + 3], w, true);
                yw[j] = (unsigned)w;
            }
            float vpx = v_prot[p * 3 + 0], vpy = v_prot[p * 3 + 1], vpz = v_prot[p * 3 + 2];
            float njx = prot_vec[p * 3 + 0], njy = prot_vec[p * 3 + 1], njz = prot_vec[p * 3 + 2];
            uint4 gr;
            gr.x = bf16r(vpx) | (bf16r(vpy) << 16);
            gr.y = bf16r(vpz) | (bf16r(njx) << 16);
            gr.z = bf16r(njy) | (bf16r(njz) << 16);
            gr.w = 0;
            uint4* d4 = reinterpret_cast<uint4*>(yrec + ((size_t)bb * NP + p) * 16);
            d4[0] = make_uint4(yw[0], yw[1], yw[2], yw[3]);
            d4[1] = make_uint4(yw[4], yw[5], yw[6], yw[7]);
            d4[2] = gr;
        } else {
            unsigned yw[16];
            #pragma unroll
            for (int j = 0; j < 16; ++j)
                yw[j] = bf16r(h[2 * j]) | (bf16r(h[2 * j + 1]) << 16);
            uint4* d4 = reinterpret_cast<uint4*>(ypb + ((size_t)bb * NP + p) * IN_C);
            d4[0] = make_uint4(yw[0], yw[1], yw[2], yw[3]);
            d4[1] = make_uint4(yw[4], yw[5], yw[6], yw[7]);
            d4[2] = make_uint4(yw[8], yw[9], yw[10], yw[11]);
            d4[3] = make_uint4(yw[12], yw[13], yw[14], yw[15]);
        }
    } else {
        if (!do_dna) return;
        int t2 = t - NP4;
        int q = t2 / NBpad;
        if (q >= 11) return;
        int idx = t2 - q * NBpad;
        if (idx >= NB) return;
        int g, m;
        if (q < 2)      { g = 0; m = q ? 10 : 0; }
        else if (q < 4) { g = 1; m = (q == 2) ? 1 : 9; }
        else if (q < 8) { g = 2; m = 2 + (q - 4); }
        else            { g = 3; m = 6 + (q - 8); }
        int bb = __builtin_amdgcn_readfirstlane(g);
        int dn = idx * 11 + m;
        const float* Wa = W1 + bb * (IN_F * IN_C);
        const float* ba = b1 + bb * IN_C;
        #pragma unroll
        for (int c = 0; c < IN_C; ++c) h[c] = ba[c];
        const float4* xd = reinterpret_cast<const float4*>(x_dna + (size_t)dn * IN_C);
        #pragma unroll
        for (int kk = 0; kk < 8; ++kk) {
            float4 xv = xd[kk];
            float fs[4] = {xv.x, xv.y, xv.z, xv.w};
            #pragma unroll
            for (int j = 0; j < 4; ++j)
                #pragma unroll
                for (int c = 0; c < IN_C; ++c)
                    h[c] = fmaf(fs[j], Wa[(36 + kk * 4 + j) * IN_C + c], h[c]);
        }
        unsigned yw[16];
        #pragma unroll
        for (int j = 0; j < 16; ++j)
            yw[j] = bf16r(h[2 * j]) | (bf16r(h[2 * j + 1]) << 16);
        uint4* d4 = reinterpret_cast<uint4*>(yd + (size_t)dn * IN_C);
        d4[0] = make_uint4(yw[0], yw[1], yw[2], yw[3]);
        d4[1] = make_uint4(yw[4], yw[5], yw[6], yw[7]);
        d4[2] = make_uint4(yw[8], yw[9], yw[10], yw[11]);
        d4[3] = make_uint4(yw[12], yw[13], yw[14], yw[15]);
    }
}

// ======================= FAST-PATH CSR BUILD =================================
__global__ __launch_bounds__(256) void k_passA(
    const int* __restrict__ esrc, const int* __restrict__ edst, int E,
    int nbkt, int* __restrict__ gcur, unsigned* __restrict__ stage)
{
    __shared__ unsigned rec[TILE_A];
    __shared__ unsigned short bkt[TILE_A];
    __shared__ int hist[NBKT_MAX];
    __shared__ int hscan[NBKT_MAX];
    __shared__ int cnt[NBKT_MAX];
    __shared__ int gpos[NBKT_MAX];
    __shared__ int chbase[8];

    int base = blockIdx.x * TILE_A;
    int n = E - base; if (n > TILE_A) n = TILE_A;
    if (n <= 0) return;

    for (int i = threadIdx.x; i < nbkt; i += 256) hist[i] = 0;
    __syncthreads();

    unsigned myrec[16];
    int mybkt[16];
    #pragma unroll
    for (int k = 0; k < 16; ++k) {
        int i = threadIdx.x + k * 256;
        mybkt[k] = -1;
        if (i < n) {
            int s = esrc[base + i];
            int d = edst[base + i];
            int b = d >> BK_SHIFT;
            myrec[k] = ((unsigned)(d & ((1 << BK_SHIFT) - 1)) << 17) | (unsigned)s;
            mybkt[k] = b;
            atomicAdd(&hist[b], 1);
        }
    }
    __syncthreads();

    {
        int lane = threadIdx.x & 63, w = threadIdx.x >> 6;
        int nch = (nbkt + 63) >> 6;
        for (int ch = w; ch < nch; ch += 4) {
            int idx = (ch << 6) + lane;
            int v = (idx < nbkt) ? hist[idx] : 0;
            int inc = v;
            #pragma unroll
            for (int d = 1; d < 64; d <<= 1) {
                int u = __shfl_up(inc, d, 64);
                if (lane >= d) inc += u;
            }
            if (idx < nbkt) hscan[idx] = inc - v;
            if (lane == 63) chbase[ch] = inc;
        }
        __syncthreads();
        if (threadIdx.x == 0) {
            int s = 0;
            for (int ch = 0; ch < nch; ++ch) { int t2 = chbase[ch]; chbase[ch] = s; s += t2; }
        }
        __syncthreads();
        for (int i = threadIdx.x; i < nbkt; i += 256) {
            int v = hscan[i] + chbase[i >> 6];
            hscan[i] = v;
            cnt[i] = v;
        }
    }
    for (int b2 = threadIdx.x; b2 < nbkt; b2 += 256) {
        int c = hist[b2];
        if (c > 0) gpos[b2] = b2 * BCAP + atomicAdd(&gcur[b2], c);
    }
    __syncthreads();

    #pragma unroll
    for (int k = 0; k < 16; ++k) {
        if (mybkt[k] >= 0) {
            int p = atomicAdd(&cnt[mybkt[k]], 1);
            rec[p] = myrec[k];
            bkt[p] = (unsigned short)mybkt[k];
        }
    }
    __syncthreads();

    for (int i = threadIdx.x; i < n; i += 256) {
        int b2 = bkt[i];
        stage[gpos[b2] + (i - hscan[b2])] = rec[i];
    }
}

__global__ __launch_bounds__(256) void k_passB2(
    const unsigned* __restrict__ stage, const int* __restrict__ gcur,
    int nbkt, int ND,
    int* __restrict__ counts, int* __restrict__ rowend,
    int* __restrict__ pool_src, int* __restrict__ hist)
{
    __shared__ int lcnt[512];
    __shared__ int lpre[512];
    __shared__ int lh[256];
    __shared__ int wsum[4];
    __shared__ int spp[4];
    __shared__ int s_pstart;

    int b = blockIdx.x;

    {
        int partial = 0;
        for (int i = threadIdx.x; i < b; i += 256) partial += gcur[i];
        #pragma unroll
        for (int d = 1; d < 64; d <<= 1) partial += __shfl_xor(partial, d, 64);
        int lane = threadIdx.x & 63, w = threadIdx.x >> 6;
        if (lane == 0) spp[w] = partial;
    }
    lcnt[threadIdx.x] = 0;
    lcnt[threadIdx.x + 256] = 0;
    lh[threadIdx.x] = 0;
    __syncthreads();
    if (threadIdx.x == 0) s_pstart = spp[0] + spp[1] + spp[2] + spp[3];
    __syncthreads();

    int cnt = gcur[b];
    int pstart = s_pstart;
    int dbase = b << BK_SHIFT;

    for (int i = threadIdx.x; i < cnt; i += 256)
        atomicAdd(&lcnt[stage[(size_t)b * BCAP + i] >> 17], 1);
    __syncthreads();

    int e0 = lcnt[2 * threadIdx.x], e1 = lcnt[2 * threadIdx.x + 1];
    int s = e0 + e1;
    int lane = threadIdx.x & 63, w = threadIdx.x >> 6;
    int inc = s;
    #pragma unroll
    for (int d = 1; d < 64; d <<= 1) {
        int u = __shfl_up(inc, d, 64);
        if (lane >= d) inc += u;
    }
    if (lane == 63) wsum[w] = inc;
    __syncthreads();
    if (threadIdx.x == 0) {
        int a = 0;
        #pragma unroll
        for (int g = 0; g < 4; ++g) { int tmp = wsum[g]; wsum[g] = a; a += tmp; }
    }
    __syncthreads();
    int excl = inc - s + wsum[w];
    lpre[2 * threadIdx.x]     = excl;
    lpre[2 * threadIdx.x + 1] = excl + e0;

    #pragma unroll
    for (int k = 0; k < 2; ++k) {
        int nid = 2 * threadIdx.x + k;
        int node = dbase + nid;
        if (node < ND) {
            int c = lcnt[nid];
            counts[node] = c;
            rowend[node] = pstart + lpre[nid] + c;
            int cc = c > 63 ? 63 : c;
            atomicAdd(&lh[branch_of(node % 11) * 64 + (63 - cc)], 1);
        }
    }
    __syncthreads();
    if (lh[threadIdx.x]) atomicAdd(&hist[threadIdx.x], lh[threadIdx.x]);

    for (int i = threadIdx.x; i < cnt; i += 256) {
        unsigned r = stage[(size_t)b * BCAP + i];
        int nid = r >> 17;
        int pos = atomicAdd(&lpre[nid], 1);
        pool_src[pstart + pos] = (int)(r & 0x1FFFFu);
    }
}

// fused tail: blocks [0,nbA) = assign (LDS-aggregated ranks!);
//             blocks [nbA,..) = precompute. Block 0 writes pbs + pad holes.
__global__ __launch_bounds__(256) void k_tail(
    const int* __restrict__ counts, const int* __restrict__ hist,
    int* __restrict__ cur, int* __restrict__ pbs,
    int* __restrict__ node_order, int ND, int nbA,
    const float* __restrict__ x_prot, const float* __restrict__ x_dna,
    const float* __restrict__ v_prot, const float* __restrict__ prot_vec,
    const float* __restrict__ W1, const float* __restrict__ b1,
    int NP, int NPpad, int NB, int NBpad,
    unsigned* __restrict__ yrec, unsigned short* __restrict__ yd)
{
    if ((int)blockIdx.x >= nbA) {
        int t = (blockIdx.x - nbA) * 256 + threadIdx.x;
        precomp_body(t, x_prot, x_dna, v_prot, prot_vec, W1, b1,
                     NP, NPpad, NB, NBpad, 1, 1, yrec, nullptr, yd);
        return;
    }

    __shared__ int sh_scan[256];
    __shared__ int sh_gb[5];
    __shared__ int sh_ge[4];
    __shared__ int gsum[4];
    __shared__ int lh[256];
    __shared__ int lbase[256];

    int lane = threadIdx.x & 63;
    int w = threadIdx.x >> 6;
    int v = hist[threadIdx.x];
    int inc = v;
    #pragma unroll
    for (int d = 1; d < 64; d <<= 1) {
        int u = __shfl_up(inc, d, 64);
        if (lane >= d) inc += u;
    }
    if (lane == 63) gsum[w] = inc;
    lh[threadIdx.x] = 0;
    __syncthreads();
    if (threadIdx.x == 0) {
        int base = 0;
        #pragma unroll
        for (int g = 0; g < 4; ++g) {
            sh_gb[g] = base;
            sh_ge[g] = base + gsum[g];
            base = (base + gsum[g] + 31) & ~31;   // 32-node aligned group base
        }
        sh_gb[4] = base;
    }
    __syncthreads();
    sh_scan[threadIdx.x] = sh_gb[w] + inc - v;
    __syncthreads();

    // LDS-aggregated ranks (R13 scheme): one global atomic per bin per block
    int t = blockIdx.x * 256 + threadIdx.x;
    bool vld = (t < ND);
    int bin = 0, rank = 0;
    if (vld) {
        int g = branch_of(t % 11);
        int c = counts[t]; c = c > 63 ? 63 : c;
        bin = g * 64 + (63 - c);
        rank = atomicAdd(&lh[bin], 1);
    }
    __syncthreads();
    int cnt = lh[threadIdx.x];
    if (cnt > 0) lbase[threadIdx.x] = atomicAdd(&cur[threadIdx.x], cnt);
    __syncthreads();
    if (vld) node_order[sh_scan[bin] + lbase[bin] + rank] = t;

    if (blockIdx.x == 0) {
        if (threadIdx.x < 5) pbs[threadIdx.x] = sh_gb[threadIdx.x];
        if (threadIdx.x < 128) {
            int g = threadIdx.x >> 5, k = threadIdx.x & 31;
            int pos = sh_ge[g] + k;
            if (pos < sh_gb[g + 1]) node_order[pos] = -1;  // pad holes
        }
    }
}

// ======================= LEGACY CSR BUILD (fallback) =========================
__global__ void k_count(const int* __restrict__ edst, int E, int* counts) {
    int t = blockIdx.x * blockDim.x + threadIdx.x;
    if (t >= E) return;
    atomicAdd(&counts[edst[t]], 1);
}

__global__ __launch_bounds__(1024) void k_scan1(const int* __restrict__ counts,
                                                int NN, int NDp, int* cursor,
                                                int* blk, int* hist,
                                                int* node_order) {
    __shared__ int wsum[16];
    __shared__ int lh[256];
    if (threadIdx.x < 256) lh[threadIdx.x] = 0;
    __syncthreads();
    int t = blockIdx.x * 1024 + threadIdx.x;
    int lane = threadIdx.x & 63;
    int wid = threadIdx.x >> 6;
    int c = (t < NN) ? counts[t] : 0;
    if (t < NN) {
        int g = branch_of(t % 11);
        int cc = c > 63 ? 63 : c;
        atomicAdd(&lh[g * 64 + (63 - cc)], 1);
    }
    if (t < NDp) node_order[t] = -1;
    int inc = c;
    #pragma unroll
    for (int d = 1; d < 64; d <<= 1) {
        int v = __shfl_up(inc, d, 64);
        if (lane >= d) inc += v;
    }
    if (lane == 63) wsum[wid] = inc;
    __syncthreads();
    if (threadIdx.x < 16) {
        int v = wsum[threadIdx.x];
        int wi = v;
        #pragma unroll
        for (int d = 1; d < 16; d <<= 1) {
            int u = __shfl_up(wi, d, 64);
            if (threadIdx.x >= d) wi += u;
        }
        wsum[threadIdx.x] = wi - v;
        if (threadIdx.x == 15) blk[blockIdx.x] = wi;
    }
    __syncthreads();
    if (t < NN) cursor[t] = inc - c + wsum[wid];
    if (threadIdx.x < 256 && lh[threadIdx.x])
        atomicAdd(&hist[threadIdx.x], lh[threadIdx.x]);
}

__global__ __launch_bounds__(256) void k_scan2(int* blk, int nblk) {
    __shared__ int wsum[4];
    int lane = threadIdx.x & 63;
    int wid = threadIdx.x >> 6;
    int v = (threadIdx.x < nblk) ? blk[threadIdx.x] : 0;
    int inc = v;
    #pragma unroll
    for (int d = 1; d < 64; d <<= 1) {
        int u = __shfl_up(inc, d, 64);
        if (lane >= d) inc += u;
    }
    if (lane == 63) wsum[wid] = inc;
    __syncthreads();
    if (threadIdx.x < 4) {
        int w = wsum[threadIdx.x];
        int wi = w;
        #pragma unroll
        for (int d = 1; d < 4; d <<= 1) {
            int u = __shfl_up(wi, d, 64);
            if (threadIdx.x >= d) wi += u;
        }
        wsum[threadIdx.x] = wi - w;
    }
    __syncthreads();
    if (threadIdx.x < nblk) blk[threadIdx.x] = inc - v + wsum[wid];
}

__global__ __launch_bounds__(1024) void k_scan3(int* cursor, const int* blk, int NN) {
    int t = blockIdx.x * 1024 + threadIdx.x;
    if (t >= NN) return;
    cursor[t] += blk[blockIdx.x];
}

__global__ void k_fill(const int* __restrict__ esrc, const int* __restrict__ edst,
                       int E, int* cursor, int* __restrict__ pool_src) {
    int t = blockIdx.x * blockDim.x + threadIdx.x;
    if (t >= E) return;
    int pos = atomicAdd(&cursor[edst[t]], 1);
    pool_src[pos] = esrc[t];
}

__global__ __launch_bounds__(256) void k_padscan2(int* hist, int* pbs) {
    __shared__ int gsum[4];
    __shared__ int gbase[5];
    int lane = threadIdx.x & 63;
    int w = threadIdx.x >> 6;
    int v = hist[threadIdx.x];
    int inc = v;
    #pragma unroll
    for (int d = 1; d < 64; d <<= 1) {
        int u = __shfl_up(inc, d, 64);
        if (lane >= d) inc += u;
    }
    if (lane == 63) gsum[w] = inc;
    __syncthreads();
    if (threadIdx.x == 0) {
        int base = 0;
        #pragma unroll
        for (int g = 0; g < 4; ++g) {
            gbase[g] = base;
            base = (base + gsum[g] + 31) & ~31;
        }
        gbase[4] = base;
    }
    __syncthreads();
    hist[threadIdx.x] = gbase[w] + inc - v;
    if (threadIdx.x < 5) pbs[threadIdx.x] = gbase[threadIdx.x];
}

__global__ __launch_bounds__(256) void k_assign(const int* __restrict__ counts,
                                                int ND, int* cur,
                                                int* __restrict__ node_order) {
    __shared__ int lh[256];
    __shared__ int lbase[256];
    lh[threadIdx.x] = 0;
    __syncthreads();
    int t = blockIdx.x * 256 + threadIdx.x;
    bool v = (t < ND);
    int bin = 0, rank = 0;
    if (v) {
        int g = branch_of(t % 11);
        int c = counts[t]; c = c > 63 ? 63 : c;
        bin = g * 64 + (63 - c);
        rank = atomicAdd(&lh[bin], 1);
    }
    __syncthreads();
    int cnt = lh[threadIdx.x];
    if (cnt > 0) lbase[threadIdx.x] = atomicAdd(&cur[threadIdx.x], cnt);
    __syncthreads();
    if (v) node_order[lbase[bin] + rank] = t;
}

__global__ __launch_bounds__(256) void k_precomp(
    const float* __restrict__ x_prot, const float* __restrict__ x_dna,
    const float* __restrict__ v_prot, const float* __restrict__ prot_vec,
    const float* __restrict__ W1, const float* __restrict__ b1,
    int NP, int NPpad, int NB, int NBpad, int do_dna, int fp8mode,
    unsigned* __restrict__ yrec, unsigned short* __restrict__ ypb,
    unsigned short* __restrict__ yd)
{
    int t = blockIdx.x * 256 + threadIdx.x;
    precomp_body(t, x_prot, x_dna, v_prot, prot_vec, W1, b1,
                 NP, NPpad, NB, NBpad, do_dna, fp8mode, yrec, ypb, yd);
}

// ======================= MFMA MAIN ===========================================
__global__ __launch_bounds__(256) void k_mfma(
    const float* __restrict__ v_dna, const float* __restrict__ dna_vec,
    const float* __restrict__ W1, const float* __restrict__ W2,
    const float* __restrict__ b2,
    const int* __restrict__ node_order, const int* __restrict__ rowend,
    const int* __restrict__ counts, const int* __restrict__ pool_src,
    const int* __restrict__ pbs,
    const unsigned* __restrict__ yrec, const unsigned short* __restrict__ yd,
    int NP, float* __restrict__ out, float* __restrict__ conv, int NDp)
{
    int nblk = gridDim.x;
    int q8 = nblk >> 3, r8 = nblk & 7;
    int x = blockIdx.x & 7, bidx = blockIdx.x >> 3;
    int lb = (x < r8 ? x * (q8 + 1) : r8 * (q8 + 1) + (x - r8) * q8) + bidx;

    int t = lb * 256 + threadIdx.x;
    int lane = threadIdx.x & 63;
    int hi = lane >> 5;
    int col = lane & 31;
    int pid = t >> 1;
    int sub = t & 1;

    int pb1 = pbs[1], pb2v = pbs[2], pb3 = pbs[3], pb4 = pbs[4];
    int g = (pid >= pb1) + (pid >= pb2v) + (pid >= pb3);
    int bb = __builtin_amdgcn_readfirstlane(g);

    int dst = (pid < pb4) ? node_order[pid] : -1;   // pb4 32-aligned: wave-safe
    bool vnode = (dst >= 0);
    int dsafe = vnode ? dst : 0;
    int n_all = vnode ? counts[dsafe] : 0;
    int start = vnode ? (rowend[dsafe] - n_all) : 0;

    const float* Wp = W1 + bb * (IN_F * IN_C) + 32 * IN_C;
    const float* Wb = W2 + bb * (IN_C * IN_C);
    float b2c = b2[bb * IN_C + col];

    U4F B0u, B1u;
    #pragma unroll
    for (int j = 0; j < 4; ++j) {
        int k0 = hi * 8 + 2 * j;
        B0u.u[j] = cvtpk_bf16(Wb[k0 * IN_C + col],        Wb[(k0 + 1) * IN_C + col]);
        B1u.u[j] = cvtpk_bf16(Wb[(16 + k0) * IN_C + col], Wb[(17 + k0) * IN_C + col]);
    }

    float vdx = v_dna[dsafe * 3 + 0], vdy = v_dna[dsafe * 3 + 1], vdz = v_dna[dsafe * 3 + 2];
    float nix = dna_vec[dsafe * 3 + 0], niy = dna_vec[dsafe * 3 + 1], niz = dna_vec[dsafe * 3 + 2];

    unsigned ydw[16];
    {
        const uint4* ydv = reinterpret_cast<const uint4*>(yd + (size_t)dsafe * IN_C);
        uint4 w0 = ydv[0], w1 = ydv[1], w2 = ydv[2], w3 = ydv[3];
        *reinterpret_cast<uint4*>(&ydw[0])  = w0;
        *reinterpret_cast<uint4*>(&ydw[4])  = w1;
        *reinterpret_cast<uint4*>(&ydw[8])  = w2;
        *reinterpret_cast<uint4*>(&ydw[12]) = w3;
    }

    float acc[16];
    #pragma unroll
    for (int i = 0; i < 16; ++i) acc[i] = 0.0f;

    int niter = (n_all + 1) >> 1;
    #pragma unroll
    for (int d = 1; d < 64; d <<= 1) {
        int o = __shfl_xor(niter, d, 64);
        niter = niter > o ? niter : o;
    }

    unsigned ywc[8];
    unsigned gwc[4];
    if (niter > 0) {
        bool v0 = vnode && (sub < n_all);
        int off0 = v0 ? (start + sub) : 0;
        int src0 = pool_src[off0];
        const uint4* yv = reinterpret_cast<const uint4*>(yrec + ((size_t)bb * NP + src0) * 16);
        uint4 y0 = yv[0], y1 = yv[1], g2 = yv[2];
        *reinterpret_cast<uint4*>(&ywc[0]) = y0;
        *reinterpret_cast<uint4*>(&ywc[4]) = y1;
        *reinterpret_cast<uint4*>(&gwc[0]) = g2;
    }

    for (int it = 0; it < niter; ++it) {
        bool valid = vnode && (2 * it + sub < n_all);
        unsigned long long vm = __ballot(valid);

        int it1 = it + 1;
        bool vn = (it1 < niter) && vnode && (2 * it1 + sub < n_all);
        int offn = vn ? (start + 2 * it1 + sub) : 0;
        int src_n = pool_src[offn];
        const uint4* yvn = reinterpret_cast<const uint4*>(yrec + ((size_t)bb * NP + src_n) * 16);
        uint4 n0 = yvn[0], n1 = yvn[1], n2 = yvn[2];

        float vpx = bflo(gwc[0]), vpy = bfhi(gwc[0]);
        float vpz = bflo(gwc[1]), njx = bfhi(gwc[1]);
        float njy = bflo(gwc[2]), njz = bfhi(gwc[2]);
        float dx = vpx - vdx, dy = vpy - vdy, dz = vpz - vdz;
        float pf0 = sqrtf(dx * dx + dy * dy + dz * dz);
        float pf1 = angf(nix, niy, niz, dx, dy, dz);
        float pf2 = angf(njx, njy, njz, dx, dy, dz);
        float pf3 = angf(nix, niy, niz, njx, njy, njz);

        unsigned p[16];
        #pragma unroll
        for (int jj = 0; jj < 8; ++jj) {
            f32x2v f01 = __builtin_amdgcn_cvt_pk_f32_fp8((int)ywc[jj], false);
            f32x2v f23 = __builtin_amdgcn_cvt_pk_f32_fp8((int)ywc[jj], true);
            int c0 = 4 * jj;
            float a0 = bflo(ydw[2 * jj])     + f01[0];
            float a1 = bfhi(ydw[2 * jj])     + f01[1];
            float a2 = bflo(ydw[2 * jj + 1]) + f23[0];
            float a3 = bfhi(ydw[2 * jj + 1]) + f23[1];
            a0 = fmaf(pf0, Wp[0 * IN_C + c0],     a0);
            a0 = fmaf(pf1, Wp[1 * IN_C + c0],     a0);
            a0 = fmaf(pf2, Wp[2 * IN_C + c0],     a0);
            a0 = fmaf(pf3, Wp[3 * IN_C + c0],     a0);
            a1 = fmaf(pf0, Wp[0 * IN_C + c0 + 1], a1);
            a1 = fmaf(pf1, Wp[1 * IN_C + c0 + 1], a1);
            a1 = fmaf(pf2, Wp[2 * IN_C + c0 + 1], a1);
            a1 = fmaf(pf3, Wp[3 * IN_C + c0 + 1], a1);
            a2 = fmaf(pf0, Wp[0 * IN_C + c0 + 2], a2);
            a2 = fmaf(pf1, Wp[1 * IN_C + c0 + 2], a2);
            a2 = fmaf(pf2, Wp[2 * IN_C + c0 + 2], a2);
            a2 = fmaf(pf3, Wp[3 * IN_C + c0 + 2], a2);
            a3 = fmaf(pf0, Wp[0 * IN_C + c0 + 3], a3);
            a3 = fmaf(pf1, Wp[1 * IN_C + c0 + 3], a3);
            a3 = fmaf(pf2, Wp[2 * IN_C + c0 + 3], a3);
            a3 = fmaf(pf3, Wp[3 * IN_C + c0 + 3], a3);
            p[2 * jj]     = cvtpk_bf16(fmaxf(a0, 0.0f), fmaxf(a1, 0.0f));
            p[2 * jj + 1] = cvtpk_bf16(fmaxf(a2, 0.0f), fmaxf(a3, 0.0f));
        }

        unsigned q[16];
        #pragma unroll
        for (int j = 0; j < 16; ++j)
            q[j] = (unsigned)__shfl_xor((int)p[j], 32, 64);

        U4F a00, a01, a10, a11;
        #pragma unroll
        for (int d2 = 0; d2 < 4; ++d2) {
            a00.u[d2] = hi ? q[4 + d2]  : p[d2];
            a01.u[d2] = hi ? q[12 + d2] : p[8 + d2];
            a10.u[d2] = hi ? p[4 + d2]  : q[d2];
            a11.u[d2] = hi ? p[12 + d2] : q[8 + d2];
        }

        unsigned long long vms = vm >> (4 * hi);

        {
            f32x16v D;
            #pragma unroll
            for (int r = 0; r < 16; ++r) D[r] = 0.0f;
            D = __builtin_amdgcn_mfma_f32_32x32x16_bf16(a00.v, B0u.v, D, 0, 0, 0);
            D = __builtin_amdgcn_mfma_f32_32x32x16_bf16(a01.v, B1u.v, D, 0, 0, 0);
            #pragma unroll
            for (int r = 0; r < 16; ++r) {
                int sh = (r & 3) + 8 * (r >> 2);
                float val = fmaxf(D[r] + b2c, 0.0f);
                bool ok = (vms >> sh) & 1ull;
                int ai = 2 * (r >> 2) + ((r & 3) >> 1);
                acc[ai] += ok ? val : 0.0f;
            }
        }
        {
            f32x16v D;
            #pragma unroll
            for (int r = 0; r < 16; ++r) D[r] = 0.0f;
            D = __builtin_amdgcn_mfma_f32_32x32x16_bf16(a10.v, B0u.v, D, 0, 0, 0);
            D = __builtin_amdgcn_mfma_f32_32x32x16_bf16(a11.v, B1u.v, D, 0, 0, 0);
            #pragma unroll
            for (int r = 0; r < 16; ++r) {
                int sh = 32 + (r & 3) + 8 * (r >> 2);
                float val = fmaxf(D[r] + b2c, 0.0f);
                bool ok = (vms >> sh) & 1ull;
                int ai = 8 + 2 * (r >> 2) + ((r & 3) >> 1);
                acc[ai] += ok ? val : 0.0f;
            }
        }

        *reinterpret_cast<uint4*>(&ywc[0]) = n0;
        *reinterpret_cast<uint4*>(&ywc[4]) = n1;
        *reinterpret_cast<uint4*>(&gwc[0]) = n2;
    }

    #pragma unroll
    for (int i = 0; i < 16; ++i) {
        int rb = i >> 3, rem = i & 7;
        int q2 = rem >> 1, u = rem & 1;
        int m = 16 * rb + 4 * q2 + 2 * hi + u;
        int dm = __shfl(dst, 2 * m, 64);
        if (dm >= 0) {
            out[(size_t)dm * IN_C + col]  = acc[i];
            conv[(size_t)dm * IN_C + col] = acc[i];
        }
    }
}

// ======================= non-MFMA fallbacks ==================================
template <int MODE>
__global__ __launch_bounds__(256) void k_nodes4(
    const float* __restrict__ x_dna, const float* __restrict__ v_dna,
    const float* __restrict__ x_prot, const float* __restrict__ v_prot,
    const float* __restrict__ prot_vec, const float* __restrict__ dna_vec,
    const float* __restrict__ W1, const float* __restrict__ b1,
    const float* __restrict__ W2, const float* __restrict__ b2,
    const int* __restrict__ node_order, const int* __restrict__ rowend,
    const int* __restrict__ counts, const int* __restrict__ pool_src,
    const int* __restrict__ pbs,
    const unsigned short* __restrict__ yp,
    int NP, float* __restrict__ out, float* __restrict__ conv, int NDp)
{
    int t = blockIdx.x * 256 + threadIdx.x;
    int pid = t >> 2;
    int sub = t & 3;
    if (pid >= NDp) return;

    int pb1 = pbs[1], pb2 = pbs[2], pb3 = pbs[3];
    int g = (pid >= pb1) + (pid >= pb2) + (pid >= pb3);
    int bb = __builtin_amdgcn_readfirstlane(g);

    int dst = node_order[pid];
    bool valid = (dst >= 0);
    int dsafe = valid ? dst : 0;

    int n_all = valid ? counts[dsafe] : 0;
    int start_all = valid ? (rowend[dsafe] - n_all) : 0;
    int nb4 = n_all >> 2, rem = n_all & 3;
    int n = nb4 + (sub < rem ? 1 : 0);
    int start = start_all + sub * nb4 + (sub < rem ? sub : rem);

    const float* Wa  = W1 + bb * (IN_F * IN_C);
    const float* Wp  = Wa + 32 * IN_C;
    const float* Wb  = W2 + bb * (IN_C * IN_C);
    const float* ba  = b1 + bb * IN_C;
    const float* bb2 = b2 + bb * IN_C;

    float vdx = v_dna[dsafe * 3 + 0], vdy = v_dna[dsafe * 3 + 1], vdz = v_dna[dsafe * 3 + 2];
    float nix = dna_vec[dsafe * 3 + 0], niy = dna_vec[dsafe * 3 + 1], niz = dna_vec[dsafe * 3 + 2];

    float h1b[IN_C];
    #pragma unroll
    for (int c = 0; c < IN_C; ++c) h1b[c] = ba[c];
    {
        const float4* xd = reinterpret_cast<const float4*>(x_dna + (size_t)dsafe * IN_C);
        #pragma unroll
        for (int kk = 0; kk < 8; ++kk) {
            float4 xv = xd[kk];
            float fs[4] = {xv.x, xv.y, xv.z, xv.w};
            #pragma unroll
            for (int j = 0; j < 4; ++j)
                #pragma unroll
                for (int c = 0; c < IN_C; ++c)
                    h1b[c] = fmaf(fs[j], Wa[(36 + kk * 4 + j) * IN_C + c], h1b[c]);
        }
    }

    float acc[IN_C];
    #pragma unroll
    for (int c = 0; c < IN_C; ++c) acc[c] = 0.0f;

    for (int k = 0; k < n; ++k) {
        int src = pool_src[start + k];
        float vpx = v_prot[src * 3 + 0], vpy = v_prot[src * 3 + 1], vpz = v_prot[src * 3 + 2];
        float njx = prot_vec[src * 3 + 0], njy = prot_vec[src * 3 + 1], njz = prot_vec[src * 3 + 2];
        float dx = vpx - vdx, dy = vpy - vdy, dz = vpz - vdz;
        float pf0 = sqrtf(dx * dx + dy * dy + dz * dz);
        float pf1 = angf(nix, niy, niz, dx, dy, dz);
        float pf2 = angf(njx, njy, njz, dx, dy, dz);
        float pf3 = angf(nix, niy, niz, njx, njy, njz);

        float h2[IN_C];
        #pragma unroll
        for (int c = 0; c < IN_C; ++c) h2[c] = bb2[c];

        if constexpr (MODE == 1) {
            unsigned yw[16];
            const uint4* ypv = reinterpret_cast<const uint4*>(yp + ((size_t)bb * NP + src) * IN_C);
            uint4 y0 = ypv[0], y1 = ypv[1], y2 = ypv[2], y3 = ypv[3];
            *reinterpret_cast<uint4*>(&yw[0])  = y0;
            *reinterpret_cast<uint4*>(&yw[4])  = y1;
            *reinterpret_cast<uint4*>(&yw[8])  = y2;
            *reinterpret_cast<uint4*>(&yw[12]) = y3;
            #pragma unroll
            for (int k2 = 0; k2 < IN_C; ++k2) {
                unsigned w = yw[k2 >> 1];
                float ypf = (k2 & 1) ? bfhi(w) : bflo(w);
                float h1v = h1b[k2] + ypf;
                h1v = fmaf(pf0, Wp[0 * IN_C + k2], h1v);
                h1v = fmaf(pf1, Wp[1 * IN_C + k2], h1v);
                h1v = fmaf(pf2, Wp[2 * IN_C + k2], h1v);
                h1v = fmaf(pf3, Wp[3 * IN_C + k2], h1v);
                float f = fmaxf(h1v, 0.0f);
                #pragma unroll
                for (int c = 0; c < IN_C; ++c)
                    h2[c] = fmaf(f, Wb[k2 * IN_C + c], h2[c]);
            }
        } else {
            float pf[4] = {pf0, pf1, pf2, pf3};
            const float4* xp = reinterpret_cast<const float4*>(x_prot + (size_t)src * IN_C);
            #pragma unroll
            for (int hh = 0; hh < 2; ++hh) {
                float h1h[16];
                #pragma unroll
                for (int c = 0; c < 16; ++c) h1h[c] = h1b[hh * 16 + c];
                #pragma unroll
                for (int kk = 0; kk < 8; ++kk) {
                    float4 xv = xp[kk];
                    float fs[4] = {xv.x, xv.y, xv.z, xv.w};
                    #pragma unroll
                    for (int j = 0; j < 4; ++j)
                        #pragma unroll
                        for (int c = 0; c < 16; ++c)
                            h1h[c] = fmaf(fs[j], Wa[(kk * 4 + j) * IN_C + hh * 16 + c], h1h[c]);
                }
                #pragma unroll
                for (int j = 0; j < 4; ++j)
                    #pragma unroll
                    for (int c = 0; c < 16; ++c)
                        h1h[c] = fmaf(pf[j], Wp[j * IN_C + hh * 16 + c], h1h[c]);
                #pragma unroll
                for (int k2 = 0; k2 < 16; ++k2) {
                    float f = fmaxf(h1h[k2], 0.0f);
                    #pragma unroll
                    for (int c = 0; c < IN_C; ++c)
                        h2[c] = fmaf(f, Wb[(hh * 16 + k2) * IN_C + c], h2[c]);
                }
            }
        }

        #pragma unroll
        for (int c = 0; c < IN_C; ++c)
            acc[c] += fmaxf(h2[c], 0.0f);
    }

    #pragma unroll
    for (int c = 0; c < IN_C; ++c)
        acc[c] += __shfl_xor(acc[c], 1, 64);
    #pragma unroll
    for (int c = 0; c < IN_C; ++c)
        acc[c] += __shfl_xor(acc[c], 2, 64);

    if (valid && sub < 2) {
        float* p = (sub ? conv : out) + (size_t)dst * IN_C;
        float4* p4 = reinterpret_cast<float4*>(p);
        #pragma unroll
        for (int qq = 0; qq < 8; ++qq) {
            float4 v;
            v.x = acc[qq * 4 + 0]; v.y = acc[qq * 4 + 1];
            v.z = acc[qq * 4 + 2]; v.w = acc[qq * 4 + 3];
            p4[qq] = v;
        }
    }
}

__global__ __launch_bounds__(256) void k_edges_fallback(
    const float* __restrict__ x_dna, const float* __restrict__ v_dna,
    const float* __restrict__ x_prot, const float* __restrict__ v_prot,
    const float* __restrict__ prot_vec, const float* __restrict__ dna_vec,
    const int* __restrict__ esrc, const int* __restrict__ edst,
    const float* __restrict__ W1, const float* __restrict__ b1,
    const float* __restrict__ W2, const float* __restrict__ b2,
    int E, float* __restrict__ conv)
{
    int t = blockIdx.x * blockDim.x + threadIdx.x;
    if (t >= E) return;
    int src = esrc[t], dst = edst[t];
    int b = branch_of(dst % 11);
    const float* Wa  = W1 + b * (IN_F * IN_C);
    const float* Wb  = W2 + b * (IN_C * IN_C);
    const float* ba  = b1 + b * IN_C;
    const float* bb2 = b2 + b * IN_C;

    float vdx = v_dna[dst * 3 + 0], vdy = v_dna[dst * 3 + 1], vdz = v_dna[dst * 3 + 2];
    float vpx = v_prot[src * 3 + 0], vpy = v_prot[src * 3 + 1], vpz = v_prot[src * 3 + 2];
    float nix = dna_vec[dst * 3 + 0], niy = dna_vec[dst * 3 + 1], niz = dna_vec[dst * 3 + 2];
    float njx = prot_vec[src * 3 + 0], njy = prot_vec[src * 3 + 1], njz = prot_vec[src * 3 + 2];
    float dx = vpx - vdx, dy = vpy - vdy, dz = vpz - vdz;
    float pf[4];
    pf[0] = sqrtf(dx * dx + dy * dy + dz * dz);
    pf[1] = angf(nix, niy, niz, dx, dy, dz);
    pf[2] = angf(njx, njy, njz, dx, dy, dz);
    pf[3] = angf(nix, niy, niz, njx, njy, njz);

    float h1[IN_C];
    #pragma unroll
    for (int c = 0; c < IN_C; ++c) h1[c] = ba[c];
    const float4* xp = reinterpret_cast<const float4*>(x_prot + (size_t)src * IN_C);
    #pragma unroll
    for (int kk = 0; kk < 8; ++kk) {
        float4 xv = xp[kk];
        float fs[4] = {xv.x, xv.y, xv.z, xv.w};
        #pragma unroll
        for (int j = 0; j < 4; ++j)
            #pragma unroll
            for (int c = 0; c < IN_C; ++c)
                h1[c] = fmaf(fs[j], Wa[(kk * 4 + j) * IN_C + c], h1[c]);
    }
    #pragma unroll
    for (int j = 0; j < 4; ++j)
        #pragma unroll
        for (int c = 0; c < IN_C; ++c)
            h1[c] = fmaf(pf[j], Wa[(32 + j) * IN_C + c], h1[c]);
    const float4* xd = reinterpret_cast<const float4*>(x_dna + (size_t)dst * IN_C);
    #pragma unroll
    for (int kk = 0; kk < 8; ++kk) {
        float4 xv = xd[kk];
        float fs[4] = {xv.x, xv.y, xv.z, xv.w};
        #pragma unroll
        for (int j = 0; j < 4; ++j)
            #pragma unroll
            for (int c = 0; c < IN_C; ++c)
                h1[c] = fmaf(fs[j], Wa[(36 + kk * 4 + j) * IN_C + c], h1[c]);
    }
    float h2[IN_C];
    #pragma unroll
    for (int c = 0; c < IN_C; ++c) h2[c] = bb2[c];
    #pragma unroll
    for (int k = 0; k < IN_C; ++k) {
        float f = fmaxf(h1[k], 0.0f);
        #pragma unroll
        for (int c = 0; c < IN_C; ++c)
            h2[c] = fmaf(f, Wb[k * IN_C + c], h2[c]);
    }
    float* cv = conv + (size_t)dst * IN_C;
    #pragma unroll
    for (int c = 0; c < IN_C; ++c)
        atomicAdd(&cv[c], fmaxf(h2[c], 0.0f));
}

extern "C" void kernel_launch(void* const* d_in, const int* in_sizes, int n_in,
                              void* d_out, int out_size, void* d_ws, size_t ws_size,
                              hipStream_t stream) {
    const float* x_dna    = (const float*)d_in[0];
    const float* v_dna    = (const float*)d_in[1];
    const float* x_prot   = (const float*)d_in[2];
    const float* v_prot   = (const float*)d_in[3];
    const float* prot_vec = (const float*)d_in[4];
    const float* dna_vec  = (const float*)d_in[5];
    const int*   esrc     = (const int*)d_in[6];
    const int*   edst     = (const int*)d_in[7];
    const float* W1       = (const float*)d_in[8];
    const float* b1       = (const float*)d_in[9];
    const float* W2       = (const float*)d_in[10];
    const float* b2       = (const float*)d_in[11];

    const int E  = in_sizes[6];
    const int ND = in_sizes[0] / IN_C;       // N_DNA
    const int NP = in_sizes[2] / IN_C;       // N_PROT
    const int half = out_size / 2;
    float* out  = (float*)d_out;
    float* conv = out + half;

    const int NDp = (ND + 160 + 31) & ~31;
    const int nblk_scan = (NDp + 1023) / 1024;
    const int eb = (E + 255) / 256;

    // ws: counts | hist(256) | gcur(512) | cur(256) | pbs(16) | blk(256)
    //     | rowcur | node_order | pool | yrec | yd
    const size_t base_ints = (size_t)ND + 256 + 512 + 256 + 16 + 256 + ND + NDp + E;
    const size_t ws_base   = base_ints * sizeof(int);
    const size_t yp_off    = (ws_base + 255) & ~(size_t)255;
    const size_t yrec_bytes = (size_t)NP * 4 * 64;                  // 64B/record
    const size_t ypb_bytes  = (size_t)NP * 4 * IN_C * 2;            // bf16 legacy
    const size_t yd_off    = yp_off + yrec_bytes;
    const size_t yd_bytes  = (size_t)ND * IN_C * sizeof(unsigned short);

    if (ND == half / IN_C && ws_size >= ws_base && nblk_scan <= 256) {
        int* counts     = (int*)d_ws;          // ND
        int* hist       = counts + ND;         // 256
        int* gcur       = hist + 256;          // 512
        int* cur        = gcur + 512;          // 256
        int* pbs        = cur + 256;           // 16
        int* blk        = pbs + 16;            // 256 (legacy)
        int* rowcur     = blk + 256;           // ND  (rowend in fast path)
        int* node_order = rowcur + ND;         // NDp
        int* pool_src   = node_order + NDp;    // E
        unsigned*       yrec = (unsigned*)((char*)d_ws + yp_off);
        unsigned short* ypb  = (unsigned short*)((char*)d_ws + yp_off);  // legacy alias
        unsigned short* yd   = (unsigned short*)((char*)d_ws + yd_off);

        int mode = 0;
        if (ws_size >= yd_off + yd_bytes && ND % 11 == 0) mode = 2;
        else if (ws_size >= yp_off + ypb_bytes)           mode = 1;

        const int nbkt = (ND + (1 << BK_SHIFT) - 1) >> BK_SHIFT;
        const size_t stage_bytes = (size_t)nbkt * BCAP * sizeof(unsigned);
        const bool fastfill = (mode == 2) && (NP < (1 << 17)) && (nbkt <= NBKT_MAX)
                              && (stage_bytes <= yrec_bytes)
                              && (E / nbkt + 512 < BCAP);

        int NPpad = (NP + 63) & ~63;
        int NB = ND / 11;
        int NBpad = (NB + 63) & ~63;

        if (fastfill) {
            unsigned* stage = yrec;   // overlay; dead after k_passB2
            hipMemsetAsync(hist, 0, 1024 * sizeof(int), stream);
            int na = (E + TILE_A - 1) / TILE_A;
            k_passA<<<na, 256, 0, stream>>>(esrc, edst, E, nbkt, gcur, stage);
            k_passB2<<<nbkt, 256, 0, stream>>>(stage, gcur, nbkt, ND,
                                               counts, rowcur, pool_src, hist);
            int nbA = (ND + 255) / 256;
            int totP = 4 * NPpad + 11 * NBpad;
            int nbP = (totP + 255) / 256;
            k_tail<<<nbA + nbP, 256, 0, stream>>>(
                counts, hist, cur, pbs, node_order, ND, nbA,
                x_prot, x_dna, v_prot, prot_vec, W1, b1,
                NP, NPpad, NB, NBpad, yrec, yd);
        } else {
            hipMemsetAsync(counts, 0, ((size_t)ND + 256) * sizeof(int), stream);
            k_count<<<eb, 256, 0, stream>>>(edst, E, counts);
            k_scan1<<<nblk_scan, 1024, 0, stream>>>(counts, ND, NDp, rowcur, blk,
                                                    hist, node_order);
            k_scan2<<<1, 256, 0, stream>>>(blk, nblk_scan);
            k_scan3<<<nblk_scan, 1024, 0, stream>>>(rowcur, blk, ND);
            k_fill<<<eb, 256, 0, stream>>>(esrc, edst, E, rowcur, pool_src);
            k_padscan2<<<1, 256, 0, stream>>>(hist, pbs);
            k_assign<<<(ND + 255) / 256, 256, 0, stream>>>(counts, ND, hist,
                                                           node_order);
            if (mode >= 1) {
                int tot = 4 * NPpad + (mode == 2 ? 11 * NBpad : 0);
                k_precomp<<<(tot + 255) / 256, 256, 0, stream>>>(
                    x_prot, x_dna, v_prot, prot_vec, W1, b1,
                    NP, NPpad, NB, NBpad, mode == 2, mode == 2,
                    yrec, ypb, yd);
            }
        }

        if (mode == 2) {
            int nbm = (2 * NDp + 255) / 256;
            k_mfma<<<nbm, 256, 0, stream>>>(
                v_dna, dna_vec, W1, W2, b2,
                node_order, rowcur, counts, pool_src, pbs,
                yrec, yd, NP, out, conv, NDp);
        } else if (mode == 1) {
            int nb4 = (4 * NDp + 255) / 256;
            k_nodes4<1><<<nb4, 256, 0, stream>>>(
                x_dna, v_dna, x_prot, v_prot, prot_vec, dna_vec,
                W1, b1, W2, b2, node_order, rowcur, counts, pool_src, pbs,
                ypb, NP, out, conv, NDp);
        } else {
            int nb4 = (4 * NDp + 255) / 256;
            k_nodes4<0><<<nb4, 256, 0, stream>>>(
                x_dna, v_dna, x_prot, v_prot, prot_vec, dna_vec,
                W1, b1, W2, b2, node_order, rowcur, counts, pool_src, pbs,
                nullptr, NP, out, conv, NDp);
        }
    } else {
        hipMemsetAsync(conv, 0, (size_t)half * sizeof(float), stream);
        k_edges_fallback<<<eb, 256, 0, stream>>>(
            x_dna, v_dna, x_prot, v_prot, prot_vec, dna_vec,
            esrc, edst, W1, b1, W2, b2, E, conv);
        hipMemcpyAsync(out, conv, (size_t)half * sizeof(float),
                       hipMemcpyDeviceToDevice, stream);
    }
}

// Round 17
// 158.241 us; speedup vs baseline: 2.8724x; 1.0945x over previous
//
#include <hip/hip_runtime.h>

// ---------------------------------------------------------------------------
// BiNet R17 = R16 with yd reverted to bf16 (per the R16 revert plan):
//   R16's fp8 yd failed absmax 1.19: yd quantization error is PER-NODE
//   CONSTANT -> adds coherently over all ~7 edges of a node (no averaging,
//   unlike yp whose per-edge src errors are independent).
//   drec[dst] = 128B {bf16 yd 64B | bf16 node-geo 12B | pad}: 2 line fills
//   per node (R15 was 3: yd + v_dna + dna_vec lines).
//   Kept from R16: prot precomp reads x_prot once for all 4 branches;
//   64B yrec; fused build pipeline.
// ---------------------------------------------------------------------------

#define IN_C 32
#define IN_F 68
#define TILE_A 4096
#define BK_SHIFT 9
#define NBKT_MAX 448
#define BCAP 6144

using bf16x8v = __attribute__((ext_vector_type(8))) short;
using f32x16v = __attribute__((ext_vector_type(16))) float;
using f32x2v  = __attribute__((ext_vector_type(2))) float;

union U4F { unsigned u[4]; bf16x8v v; };

__device__ __forceinline__ unsigned cvtpk_bf16(float a, float b) {
    unsigned r;
    asm("v_cvt_pk_bf16_f32 %0, %1, %2" : "=v"(r) : "v"(a), "v"(b));
    return r;
}
__device__ __forceinline__ float bflo(unsigned u) { return __uint_as_float(u << 16); }
__device__ __forceinline__ float bfhi(unsigned u) { return __uint_as_float(u & 0xffff0000u); }

__device__ __forceinline__ float angf(float ax, float ay, float az,
                                      float bx, float by, float bz) {
    float cx = ay * bz - az * by;
    float cy = az * bx - ax * bz;
    float cz = ax * by - ay * bx;
    float cn = sqrtf(cx * cx + cy * cy + cz * cz);
    float dt = ax * bx + ay * by + az * bz;
    return atan2f(cn, dt);
}

__device__ __forceinline__ int branch_of(int m) {
    if (m == 0 || m == 10) return 0;
    if (m == 1 || m == 9)  return 1;
    if (m >= 2 && m <= 5)  return 2;
    return 3;
}

__device__ __forceinline__ unsigned bf16r(float f) {
    unsigned u = __float_as_uint(f);
    return (u + 0x7fffu + ((u >> 16) & 1u)) >> 16;
}

// ======================= fast-path precompute ================================
// prot: thread p computes ALL 4 branches (x_prot read once);
//       yrec[g][p] = 64B {fp8 yp 32B | bf16 src-geo 12B | pad}.
// dna:  drec[dn]   = 128B {bf16 yd 64B | bf16 node-geo 12B | pad}.
__device__ __forceinline__ void precomp_body_fast(
    int t,
    const float* __restrict__ x_prot, const float* __restrict__ x_dna,
    const float* __restrict__ v_prot, const float* __restrict__ prot_vec,
    const float* __restrict__ v_dna, const float* __restrict__ dna_vec,
    const float* __restrict__ W1, const float* __restrict__ b1,
    int NP, int NPpad, int NB, int NBpad,
    unsigned* __restrict__ yrec, unsigned* __restrict__ drec)
{
    float h[IN_C];
    if (t < NPpad) {
        int p = t;
        if (p >= NP) return;
        float xs[IN_C];
        {
            const float4* xp = reinterpret_cast<const float4*>(x_prot + (size_t)p * IN_C);
            #pragma unroll
            for (int kk = 0; kk < 8; ++kk) {
                float4 xv = xp[kk];
                xs[4 * kk + 0] = xv.x; xs[4 * kk + 1] = xv.y;
                xs[4 * kk + 2] = xv.z; xs[4 * kk + 3] = xv.w;
            }
        }
        float vpx = v_prot[p * 3 + 0], vpy = v_prot[p * 3 + 1], vpz = v_prot[p * 3 + 2];
        float njx = prot_vec[p * 3 + 0], njy = prot_vec[p * 3 + 1], njz = prot_vec[p * 3 + 2];
        uint4 gr;
        gr.x = bf16r(vpx) | (bf16r(vpy) << 16);
        gr.y = bf16r(vpz) | (bf16r(njx) << 16);
        gr.z = bf16r(njy) | (bf16r(njz) << 16);
        gr.w = 0;
        #pragma unroll 1
        for (int g = 0; g < 4; ++g) {
            const float* Wa = W1 + g * (IN_F * IN_C);
            #pragma unroll
            for (int c = 0; c < IN_C; ++c) h[c] = 0.0f;
            #pragma unroll
            for (int k = 0; k < IN_C; ++k)
                #pragma unroll
                for (int c = 0; c < IN_C; ++c)
                    h[c] = fmaf(xs[k], Wa[k * IN_C + c], h[c]);
            unsigned yw[8];
            #pragma unroll
            for (int j = 0; j < 8; ++j) {
                int w = 0;
                w = __builtin_amdgcn_cvt_pk_fp8_f32(h[4 * j],     h[4 * j + 1], w, false);
                w = __builtin_amdgcn_cvt_pk_fp8_f32(h[4 * j + 2], h[4 * j + 3], w, true);
                yw[j] = (unsigned)w;
            }
            uint4* d4 = reinterpret_cast<uint4*>(yrec + ((size_t)g * NP + p) * 16);
            d4[0] = make_uint4(yw[0], yw[1], yw[2], yw[3]);
            d4[1] = make_uint4(yw[4], yw[5], yw[6], yw[7]);
            d4[2] = gr;
        }
    } else {
        int t2 = t - NPpad;
        int q = t2 / NBpad;                       // wave-uniform (NBpad%64==0)
        if (q >= 11) return;
        int idx = t2 - q * NBpad;
        if (idx >= NB) return;
        int g, m;
        if (q < 2)      { g = 0; m = q ? 10 : 0; }
        else if (q < 4) { g = 1; m = (q == 2) ? 1 : 9; }
        else if (q < 8) { g = 2; m = 2 + (q - 4); }
        else            { g = 3; m = 6 + (q - 8); }
        int bb = __builtin_amdgcn_readfirstlane(g);
        int dn = idx * 11 + m;
        const float* Wa = W1 + bb * (IN_F * IN_C);
        const float* ba = b1 + bb * IN_C;
        #pragma unroll
        for (int c = 0; c < IN_C; ++c) h[c] = ba[c];
        const float4* xd = reinterpret_cast<const float4*>(x_dna + (size_t)dn * IN_C);
        #pragma unroll
        for (int kk = 0; kk < 8; ++kk) {
            float4 xv = xd[kk];
            float fs[4] = {xv.x, xv.y, xv.z, xv.w};
            #pragma unroll
            for (int j = 0; j < 4; ++j)
                #pragma unroll
                for (int c = 0; c < IN_C; ++c)
                    h[c] = fmaf(fs[j], Wa[(36 + kk * 4 + j) * IN_C + c], h[c]);
        }
        unsigned yw[16];
        #pragma unroll
        for (int j = 0; j < 16; ++j)
            yw[j] = bf16r(h[2 * j]) | (bf16r(h[2 * j + 1]) << 16);
        float vdx = v_dna[dn * 3 + 0], vdy = v_dna[dn * 3 + 1], vdz = v_dna[dn * 3 + 2];
        float nix = dna_vec[dn * 3 + 0], niy = dna_vec[dn * 3 + 1], niz = dna_vec[dn * 3 + 2];
        uint4 gr;
        gr.x = bf16r(vdx) | (bf16r(vdy) << 16);
        gr.y = bf16r(vdz) | (bf16r(nix) << 16);
        gr.z = bf16r(niy) | (bf16r(niz) << 16);
        gr.w = 0;
        uint4* d4 = reinterpret_cast<uint4*>(drec + (size_t)dn * 32);
        d4[0] = make_uint4(yw[0],  yw[1],  yw[2],  yw[3]);
        d4[1] = make_uint4(yw[4],  yw[5],  yw[6],  yw[7]);
        d4[2] = make_uint4(yw[8],  yw[9],  yw[10], yw[11]);
        d4[3] = make_uint4(yw[12], yw[13], yw[14], yw[15]);
        d4[4] = gr;
    }
}

// ======================= FAST-PATH CSR BUILD =================================
__global__ __launch_bounds__(256) void k_passA(
    const int* __restrict__ esrc, const int* __restrict__ edst, int E,
    int nbkt, int* __restrict__ gcur, unsigned* __restrict__ stage)
{
    __shared__ unsigned rec[TILE_A];
    __shared__ unsigned short bkt[TILE_A];
    __shared__ int hist[NBKT_MAX];
    __shared__ int hscan[NBKT_MAX];
    __shared__ int cnt[NBKT_MAX];
    __shared__ int gpos[NBKT_MAX];
    __shared__ int chbase[8];

    int base = blockIdx.x * TILE_A;
    int n = E - base; if (n > TILE_A) n = TILE_A;
    if (n <= 0) return;

    for (int i = threadIdx.x; i < nbkt; i += 256) hist[i] = 0;
    __syncthreads();

    unsigned myrec[16];
    int mybkt[16];
    #pragma unroll
    for (int k = 0; k < 16; ++k) {
        int i = threadIdx.x + k * 256;
        mybkt[k] = -1;
        if (i < n) {
            int s = esrc[base + i];
            int d = edst[base + i];
            int b = d >> BK_SHIFT;
            myrec[k] = ((unsigned)(d & ((1 << BK_SHIFT) - 1)) << 17) | (unsigned)s;
            mybkt[k] = b;
            atomicAdd(&hist[b], 1);
        }
    }
    __syncthreads();

    {
        int lane = threadIdx.x & 63, w = threadIdx.x >> 6;
        int nch = (nbkt + 63) >> 6;
        for (int ch = w; ch < nch; ch += 4) {
            int idx = (ch << 6) + lane;
            int v = (idx < nbkt) ? hist[idx] : 0;
            int inc = v;
            #pragma unroll
            for (int d = 1; d < 64; d <<= 1) {
                int u = __shfl_up(inc, d, 64);
                if (lane >= d) inc += u;
            }
            if (idx < nbkt) hscan[idx] = inc - v;
            if (lane == 63) chbase[ch] = inc;
        }
        __syncthreads();
        if (threadIdx.x == 0) {
            int s = 0;
            for (int ch = 0; ch < nch; ++ch) { int t2 = chbase[ch]; chbase[ch] = s; s += t2; }
        }
        __syncthreads();
        for (int i = threadIdx.x; i < nbkt; i += 256) {
            int v = hscan[i] + chbase[i >> 6];
            hscan[i] = v;
            cnt[i] = v;
        }
    }
    for (int b2 = threadIdx.x; b2 < nbkt; b2 += 256) {
        int c = hist[b2];
        if (c > 0) gpos[b2] = b2 * BCAP + atomicAdd(&gcur[b2], c);
    }
    __syncthreads();

    #pragma unroll
    for (int k = 0; k < 16; ++k) {
        if (mybkt[k] >= 0) {
            int p = atomicAdd(&cnt[mybkt[k]], 1);
            rec[p] = myrec[k];
            bkt[p] = (unsigned short)mybkt[k];
        }
    }
    __syncthreads();

    for (int i = threadIdx.x; i < n; i += 256) {
        int b2 = bkt[i];
        stage[gpos[b2] + (i - hscan[b2])] = rec[i];
    }
}

__global__ __launch_bounds__(256) void k_passB2(
    const unsigned* __restrict__ stage, const int* __restrict__ gcur,
    int nbkt, int ND,
    int* __restrict__ counts, int* __restrict__ rowend,
    int* __restrict__ pool_src, int* __restrict__ hist)
{
    __shared__ int lcnt[512];
    __shared__ int lpre[512];
    __shared__ int lh[256];
    __shared__ int wsum[4];
    __shared__ int spp[4];
    __shared__ int s_pstart;

    int b = blockIdx.x;

    {
        int partial = 0;
        for (int i = threadIdx.x; i < b; i += 256) partial += gcur[i];
        #pragma unroll
        for (int d = 1; d < 64; d <<= 1) partial += __shfl_xor(partial, d, 64);
        int lane = threadIdx.x & 63, w = threadIdx.x >> 6;
        if (lane == 0) spp[w] = partial;
    }
    lcnt[threadIdx.x] = 0;
    lcnt[threadIdx.x + 256] = 0;
    lh[threadIdx.x] = 0;
    __syncthreads();
    if (threadIdx.x == 0) s_pstart = spp[0] + spp[1] + spp[2] + spp[3];
    __syncthreads();

    int cnt = gcur[b];
    int pstart = s_pstart;
    int dbase = b << BK_SHIFT;

    for (int i = threadIdx.x; i < cnt; i += 256)
        atomicAdd(&lcnt[stage[(size_t)b * BCAP + i] >> 17], 1);
    __syncthreads();

    int e0 = lcnt[2 * threadIdx.x], e1 = lcnt[2 * threadIdx.x + 1];
    int s = e0 + e1;
    int lane = threadIdx.x & 63, w = threadIdx.x >> 6;
    int inc = s;
    #pragma unroll
    for (int d = 1; d < 64; d <<= 1) {
        int u = __shfl_up(inc, d, 64);
        if (lane >= d) inc += u;
    }
    if (lane == 63) wsum[w] = inc;
    __syncthreads();
    if (threadIdx.x == 0) {
        int a = 0;
        #pragma unroll
        for (int g = 0; g < 4; ++g) { int tmp = wsum[g]; wsum[g] = a; a += tmp; }
    }
    __syncthreads();
    int excl = inc - s + wsum[w];
    lpre[2 * threadIdx.x]     = excl;
    lpre[2 * threadIdx.x + 1] = excl + e0;

    #pragma unroll
    for (int k = 0; k < 2; ++k) {
        int nid = 2 * threadIdx.x + k;
        int node = dbase + nid;
        if (node < ND) {
            int c = lcnt[nid];
            counts[node] = c;
            rowend[node] = pstart + lpre[nid] + c;
            int cc = c > 63 ? 63 : c;
            atomicAdd(&lh[branch_of(node % 11) * 64 + (63 - cc)], 1);
        }
    }
    __syncthreads();
    if (lh[threadIdx.x]) atomicAdd(&hist[threadIdx.x], lh[threadIdx.x]);

    for (int i = threadIdx.x; i < cnt; i += 256) {
        unsigned r = stage[(size_t)b * BCAP + i];
        int nid = r >> 17;
        int pos = atomicAdd(&lpre[nid], 1);
        pool_src[pstart + pos] = (int)(r & 0x1FFFFu);
    }
}

// fused tail: blocks [0,nbA) = assign (LDS-aggregated ranks);
//             blocks [nbA,..) = precompute. Block 0 writes pbs + pad holes.
__global__ __launch_bounds__(256) void k_tail(
    const int* __restrict__ counts, const int* __restrict__ hist,
    int* __restrict__ cur, int* __restrict__ pbs,
    int* __restrict__ node_order, int ND, int nbA,
    const float* __restrict__ x_prot, const float* __restrict__ x_dna,
    const float* __restrict__ v_prot, const float* __restrict__ prot_vec,
    const float* __restrict__ v_dna, const float* __restrict__ dna_vec,
    const float* __restrict__ W1, const float* __restrict__ b1,
    int NP, int NPpad, int NB, int NBpad,
    unsigned* __restrict__ yrec, unsigned* __restrict__ drec)
{
    if ((int)blockIdx.x >= nbA) {
        int t = (blockIdx.x - nbA) * 256 + threadIdx.x;
        precomp_body_fast(t, x_prot, x_dna, v_prot, prot_vec, v_dna, dna_vec,
                          W1, b1, NP, NPpad, NB, NBpad, yrec, drec);
        return;
    }

    __shared__ int sh_scan[256];
    __shared__ int sh_gb[5];
    __shared__ int sh_ge[4];
    __shared__ int gsum[4];
    __shared__ int lh[256];
    __shared__ int lbase[256];

    int lane = threadIdx.x & 63;
    int w = threadIdx.x >> 6;
    int v = hist[threadIdx.x];
    int inc = v;
    #pragma unroll
    for (int d = 1; d < 64; d <<= 1) {
        int u = __shfl_up(inc, d, 64);
        if (lane >= d) inc += u;
    }
    if (lane == 63) gsum[w] = inc;
    lh[threadIdx.x] = 0;
    __syncthreads();
    if (threadIdx.x == 0) {
        int base = 0;
        #pragma unroll
        for (int g = 0; g < 4; ++g) {
            sh_gb[g] = base;
            sh_ge[g] = base + gsum[g];
            base = (base + gsum[g] + 31) & ~31;   // 32-node aligned group base
        }
        sh_gb[4] = base;
    }
    __syncthreads();
    sh_scan[threadIdx.x] = sh_gb[w] + inc - v;
    __syncthreads();

    int t = blockIdx.x * 256 + threadIdx.x;
    bool vld = (t < ND);
    int bin = 0, rank = 0;
    if (vld) {
        int g = branch_of(t % 11);
        int c = counts[t]; c = c > 63 ? 63 : c;
        bin = g * 64 + (63 - c);
        rank = atomicAdd(&lh[bin], 1);
    }
    __syncthreads();
    int cnt = lh[threadIdx.x];
    if (cnt > 0) lbase[threadIdx.x] = atomicAdd(&cur[threadIdx.x], cnt);
    __syncthreads();
    if (vld) node_order[sh_scan[bin] + lbase[bin] + rank] = t;

    if (blockIdx.x == 0) {
        if (threadIdx.x < 5) pbs[threadIdx.x] = sh_gb[threadIdx.x];
        if (threadIdx.x < 128) {
            int g = threadIdx.x >> 5, k = threadIdx.x & 31;
            int pos = sh_ge[g] + k;
            if (pos < sh_gb[g + 1]) node_order[pos] = -1;  // pad holes
        }
    }
}

// ======================= LEGACY CSR BUILD (fallback) =========================
__global__ void k_count(const int* __restrict__ edst, int E, int* counts) {
    int t = blockIdx.x * blockDim.x + threadIdx.x;
    if (t >= E) return;
    atomicAdd(&counts[edst[t]], 1);
}

__global__ __launch_bounds__(1024) void k_scan1(const int* __restrict__ counts,
                                                int NN, int NDp, int* cursor,
                                                int* blk, int* hist,
                                                int* node_order) {
    __shared__ int wsum[16];
    __shared__ int lh[256];
    if (threadIdx.x < 256) lh[threadIdx.x] = 0;
    __syncthreads();
    int t = blockIdx.x * 1024 + threadIdx.x;
    int lane = threadIdx.x & 63;
    int wid = threadIdx.x >> 6;
    int c = (t < NN) ? counts[t] : 0;
    if (t < NN) {
        int g = branch_of(t % 11);
        int cc = c > 63 ? 63 : c;
        atomicAdd(&lh[g * 64 + (63 - cc)], 1);
    }
    if (t < NDp) node_order[t] = -1;
    int inc = c;
    #pragma unroll
    for (int d = 1; d < 64; d <<= 1) {
        int v = __shfl_up(inc, d, 64);
        if (lane >= d) inc += v;
    }
    if (lane == 63) wsum[wid] = inc;
    __syncthreads();
    if (threadIdx.x < 16) {
        int v = wsum[threadIdx.x];
        int wi = v;
        #pragma unroll
        for (int d = 1; d < 16; d <<= 1) {
            int u = __shfl_up(wi, d, 64);
            if (threadIdx.x >= d) wi += u;
        }
        wsum[threadIdx.x] = wi - v;
        if (threadIdx.x == 15) blk[blockIdx.x] = wi;
    }
    __syncthreads();
    if (t < NN) cursor[t] = inc - c + wsum[wid];
    if (threadIdx.x < 256 && lh[threadIdx.x])
        atomicAdd(&hist[threadIdx.x], lh[threadIdx.x]);
}

__global__ __launch_bounds__(256) void k_scan2(int* blk, int nblk) {
    __shared__ int wsum[4];
    int lane = threadIdx.x & 63;
    int wid = threadIdx.x >> 6;
    int v = (threadIdx.x < nblk) ? blk[threadIdx.x] : 0;
    int inc = v;
    #pragma unroll
    for (int d = 1; d < 64; d <<= 1) {
        int u = __shfl_up(inc, d, 64);
        if (lane >= d) inc += u;
    }
    if (lane == 63) wsum[wid] = inc;
    __syncthreads();
    if (threadIdx.x < 4) {
        int w = wsum[threadIdx.x];
        int wi = w;
        #pragma unroll
        for (int d = 1; d < 4; d <<= 1) {
            int u = __shfl_up(wi, d, 64);
            if (threadIdx.x >= d) wi += u;
        }
        wsum[threadIdx.x] = wi - w;
    }
    __syncthreads();
    if (threadIdx.x < nblk) blk[threadIdx.x] = inc - v + wsum[wid];
}

__global__ __launch_bounds__(1024) void k_scan3(int* cursor, const int* blk, int NN) {
    int t = blockIdx.x * 1024 + threadIdx.x;
    if (t >= NN) return;
    cursor[t] += blk[blockIdx.x];
}

__global__ void k_fill(const int* __restrict__ esrc, const int* __restrict__ edst,
                       int E, int* cursor, int* __restrict__ pool_src) {
    int t = blockIdx.x * blockDim.x + threadIdx.x;
    if (t >= E) return;
    int pos = atomicAdd(&cursor[edst[t]], 1);
    pool_src[pos] = esrc[t];
}

__global__ __launch_bounds__(256) void k_padscan2(int* hist, int* pbs) {
    __shared__ int gsum[4];
    __shared__ int gbase[5];
    int lane = threadIdx.x & 63;
    int w = threadIdx.x >> 6;
    int v = hist[threadIdx.x];
    int inc = v;
    #pragma unroll
    for (int d = 1; d < 64; d <<= 1) {
        int u = __shfl_up(inc, d, 64);
        if (lane >= d) inc += u;
    }
    if (lane == 63) gsum[w] = inc;
    __syncthreads();
    if (threadIdx.x == 0) {
        int base = 0;
        #pragma unroll
        for (int g = 0; g < 4; ++g) {
            gbase[g] = base;
            base = (base + gsum[g] + 31) & ~31;
        }
        gbase[4] = base;
    }
    __syncthreads();
    hist[threadIdx.x] = gbase[w] + inc - v;
    if (threadIdx.x < 5) pbs[threadIdx.x] = gbase[threadIdx.x];
}

__global__ __launch_bounds__(256) void k_assign(const int* __restrict__ counts,
                                                int ND, int* cur,
                                                int* __restrict__ node_order) {
    __shared__ int lh[256];
    __shared__ int lbase[256];
    lh[threadIdx.x] = 0;
    __syncthreads();
    int t = blockIdx.x * 256 + threadIdx.x;
    bool v = (t < ND);
    int bin = 0, rank = 0;
    if (v) {
        int g = branch_of(t % 11);
        int c = counts[t]; c = c > 63 ? 63 : c;
        bin = g * 64 + (63 - c);
        rank = atomicAdd(&lh[bin], 1);
    }
    __syncthreads();
    int cnt = lh[threadIdx.x];
    if (cnt > 0) lbase[threadIdx.x] = atomicAdd(&cur[threadIdx.x], cnt);
    __syncthreads();
    if (v) node_order[lbase[bin] + rank] = t;
}

// legacy bf16 yp precompute (mode-1 fallback only)
__global__ __launch_bounds__(256) void k_precomp1(
    const float* __restrict__ x_prot, const float* __restrict__ W1,
    int NP, int NPpad, unsigned short* __restrict__ ypb)
{
    int t = blockIdx.x * 256 + threadIdx.x;
    int g = t / NPpad;
    int p = t - g * NPpad;
    if (g > 3 || p >= NP) return;
    int bb = __builtin_amdgcn_readfirstlane(g);
    const float* Wa = W1 + bb * (IN_F * IN_C);
    float h[IN_C];
    #pragma unroll
    for (int c = 0; c < IN_C; ++c) h[c] = 0.0f;
    const float4* xp = reinterpret_cast<const float4*>(x_prot + (size_t)p * IN_C);
    #pragma unroll
    for (int kk = 0; kk < 8; ++kk) {
        float4 xv = xp[kk];
        float fs[4] = {xv.x, xv.y, xv.z, xv.w};
        #pragma unroll
        for (int j = 0; j < 4; ++j)
            #pragma unroll
            for (int c = 0; c < IN_C; ++c)
                h[c] = fmaf(fs[j], Wa[(kk * 4 + j) * IN_C + c], h[c]);
    }
    unsigned yw[16];
    #pragma unroll
    for (int j = 0; j < 16; ++j)
        yw[j] = bf16r(h[2 * j]) | (bf16r(h[2 * j + 1]) << 16);
    uint4* d4 = reinterpret_cast<uint4*>(ypb + ((size_t)bb * NP + p) * IN_C);
    d4[0] = make_uint4(yw[0], yw[1], yw[2], yw[3]);
    d4[1] = make_uint4(yw[4], yw[5], yw[6], yw[7]);
    d4[2] = make_uint4(yw[8], yw[9], yw[10], yw[11]);
    d4[3] = make_uint4(yw[12], yw[13], yw[14], yw[15]);
}

// ======================= MFMA MAIN ===========================================
__global__ __launch_bounds__(256) void k_mfma(
    const float* __restrict__ W1, const float* __restrict__ W2,
    const float* __restrict__ b2,
    const int* __restrict__ node_order, const int* __restrict__ rowend,
    const int* __restrict__ counts, const int* __restrict__ pool_src,
    const int* __restrict__ pbs,
    const unsigned* __restrict__ yrec, const unsigned* __restrict__ drec,
    int NP, float* __restrict__ out, float* __restrict__ conv, int NDp)
{
    int nblk = gridDim.x;
    int q8 = nblk >> 3, r8 = nblk & 7;
    int x = blockIdx.x & 7, bidx = blockIdx.x >> 3;
    int lb = (x < r8 ? x * (q8 + 1) : r8 * (q8 + 1) + (x - r8) * q8) + bidx;

    int t = lb * 256 + threadIdx.x;
    int lane = threadIdx.x & 63;
    int hi = lane >> 5;
    int col = lane & 31;
    int pid = t >> 1;
    int sub = t & 1;

    int pb1 = pbs[1], pb2v = pbs[2], pb3 = pbs[3], pb4 = pbs[4];
    int g = (pid >= pb1) + (pid >= pb2v) + (pid >= pb3);
    int bb = __builtin_amdgcn_readfirstlane(g);

    int dst = (pid < pb4) ? node_order[pid] : -1;   // pb4 32-aligned: wave-safe
    bool vnode = (dst >= 0);
    int dsafe = vnode ? dst : 0;
    int n_all = vnode ? counts[dsafe] : 0;
    int start = vnode ? (rowend[dsafe] - n_all) : 0;

    const float* Wp = W1 + bb * (IN_F * IN_C) + 32 * IN_C;
    const float* Wb = W2 + bb * (IN_C * IN_C);
    float b2c = b2[bb * IN_C + col];

    U4F B0u, B1u;
    #pragma unroll
    for (int j = 0; j < 4; ++j) {
        int k0 = hi * 8 + 2 * j;
        B0u.u[j] = cvtpk_bf16(Wb[k0 * IN_C + col],        Wb[(k0 + 1) * IN_C + col]);
        B1u.u[j] = cvtpk_bf16(Wb[(16 + k0) * IN_C + col], Wb[(17 + k0) * IN_C + col]);
    }

    // node record: 128B = {bf16 yd 64B | bf16 node geo 12B | pad}
    unsigned ydw[16];
    float vdx, vdy, vdz, nix, niy, niz;
    {
        const uint4* dv = reinterpret_cast<const uint4*>(drec + (size_t)dsafe * 32);
        uint4 d0 = dv[0], d1 = dv[1], d2 = dv[2], d3 = dv[3], d4v = dv[4];
        *reinterpret_cast<uint4*>(&ydw[0])  = d0;
        *reinterpret_cast<uint4*>(&ydw[4])  = d1;
        *reinterpret_cast<uint4*>(&ydw[8])  = d2;
        *reinterpret_cast<uint4*>(&ydw[12]) = d3;
        vdx = bflo(d4v.x); vdy = bfhi(d4v.x);
        vdz = bflo(d4v.y); nix = bfhi(d4v.y);
        niy = bflo(d4v.z); niz = bfhi(d4v.z);
    }

    float acc[16];
    #pragma unroll
    for (int i = 0; i < 16; ++i) acc[i] = 0.0f;

    int niter = (n_all + 1) >> 1;
    #pragma unroll
    for (int d = 1; d < 64; d <<= 1) {
        int o = __shfl_xor(niter, d, 64);
        niter = niter > o ? niter : o;
    }

    unsigned ywc[8];
    unsigned gwc[4];
    if (niter > 0) {
        bool v0 = vnode && (sub < n_all);
        int off0 = v0 ? (start + sub) : 0;
        int src0 = pool_src[off0];
        const uint4* yv = reinterpret_cast<const uint4*>(yrec + ((size_t)bb * NP + src0) * 16);
        uint4 y0 = yv[0], y1 = yv[1], g2 = yv[2];
        *reinterpret_cast<uint4*>(&ywc[0]) = y0;
        *reinterpret_cast<uint4*>(&ywc[4]) = y1;
        *reinterpret_cast<uint4*>(&gwc[0]) = g2;
    }

    for (int it = 0; it < niter; ++it) {
        bool valid = vnode && (2 * it + sub < n_all);
        unsigned long long vm = __ballot(valid);

        int it1 = it + 1;
        bool vn = (it1 < niter) && vnode && (2 * it1 + sub < n_all);
        int offn = vn ? (start + 2 * it1 + sub) : 0;
        int src_n = pool_src[offn];
        const uint4* yvn = reinterpret_cast<const uint4*>(yrec + ((size_t)bb * NP + src_n) * 16);
        uint4 n0 = yvn[0], n1 = yvn[1], n2 = yvn[2];

        float vpx = bflo(gwc[0]), vpy = bfhi(gwc[0]);
        float vpz = bflo(gwc[1]), njx = bfhi(gwc[1]);
        float njy = bflo(gwc[2]), njz = bfhi(gwc[2]);
        float dx = vpx - vdx, dy = vpy - vdy, dz = vpz - vdz;
        float pf0 = sqrtf(dx * dx + dy * dy + dz * dz);
        float pf1 = angf(nix, niy, niz, dx, dy, dz);
        float pf2 = angf(njx, njy, njz, dx, dy, dz);
        float pf3 = angf(nix, niy, niz, njx, njy, njz);

        // h1 = yd(bf16) + yp(fp8) + Wp.ppf, relu, pack bf16 -> p[16]
        unsigned p[16];
        #pragma unroll
        for (int jj = 0; jj < 8; ++jj) {
            f32x2v f01 = __builtin_amdgcn_cvt_pk_f32_fp8((int)ywc[jj], false);
            f32x2v f23 = __builtin_amdgcn_cvt_pk_f32_fp8((int)ywc[jj], true);
            int c0 = 4 * jj;
            float a0 = bflo(ydw[2 * jj])     + f01[0];
            float a1 = bfhi(ydw[2 * jj])     + f01[1];
            float a2 = bflo(ydw[2 * jj + 1]) + f23[0];
            float a3 = bfhi(ydw[2 * jj + 1]) + f23[1];
            a0 = fmaf(pf0, Wp[0 * IN_C + c0],     a0);
            a0 = fmaf(pf1, Wp[1 * IN_C + c0],     a0);
            a0 = fmaf(pf2, Wp[2 * IN_C + c0],     a0);
            a0 = fmaf(pf3, Wp[3 * IN_C + c0],     a0);
            a1 = fmaf(pf0, Wp[0 * IN_C + c0 + 1], a1);
            a1 = fmaf(pf1, Wp[1 * IN_C + c0 + 1], a1);
            a1 = fmaf(pf2, Wp[2 * IN_C + c0 + 1], a1);
            a1 = fmaf(pf3, Wp[3 * IN_C + c0 + 1], a1);
            a2 = fmaf(pf0, Wp[0 * IN_C + c0 + 2], a2);
            a2 = fmaf(pf1, Wp[1 * IN_C + c0 + 2], a2);
            a2 = fmaf(pf2, Wp[2 * IN_C + c0 + 2], a2);
            a2 = fmaf(pf3, Wp[3 * IN_C + c0 + 2], a2);
            a3 = fmaf(pf0, Wp[0 * IN_C + c0 + 3], a3);
            a3 = fmaf(pf1, Wp[1 * IN_C + c0 + 3], a3);
            a3 = fmaf(pf2, Wp[2 * IN_C + c0 + 3], a3);
            a3 = fmaf(pf3, Wp[3 * IN_C + c0 + 3], a3);
            p[2 * jj]     = cvtpk_bf16(fmaxf(a0, 0.0f), fmaxf(a1, 0.0f));
            p[2 * jj + 1] = cvtpk_bf16(fmaxf(a2, 0.0f), fmaxf(a3, 0.0f));
        }

        unsigned q[16];
        #pragma unroll
        for (int j = 0; j < 16; ++j)
            q[j] = (unsigned)__shfl_xor((int)p[j], 32, 64);

        U4F a00, a01, a10, a11;
        #pragma unroll
        for (int d2 = 0; d2 < 4; ++d2) {
            a00.u[d2] = hi ? q[4 + d2]  : p[d2];
            a01.u[d2] = hi ? q[12 + d2] : p[8 + d2];
            a10.u[d2] = hi ? p[4 + d2]  : q[d2];
            a11.u[d2] = hi ? p[12 + d2] : q[8 + d2];
        }

        unsigned long long vms = vm >> (4 * hi);

        {
            f32x16v D;
            #pragma unroll
            for (int r = 0; r < 16; ++r) D[r] = 0.0f;
            D = __builtin_amdgcn_mfma_f32_32x32x16_bf16(a00.v, B0u.v, D, 0, 0, 0);
            D = __builtin_amdgcn_mfma_f32_32x32x16_bf16(a01.v, B1u.v, D, 0, 0, 0);
            #pragma unroll
            for (int r = 0; r < 16; ++r) {
                int sh = (r & 3) + 8 * (r >> 2);
                float val = fmaxf(D[r] + b2c, 0.0f);
                bool ok = (vms >> sh) & 1ull;
                int ai = 2 * (r >> 2) + ((r & 3) >> 1);
                acc[ai] += ok ? val : 0.0f;
            }
        }
        {
            f32x16v D;
            #pragma unroll
            for (int r = 0; r < 16; ++r) D[r] = 0.0f;
            D = __builtin_amdgcn_mfma_f32_32x32x16_bf16(a10.v, B0u.v, D, 0, 0, 0);
            D = __builtin_amdgcn_mfma_f32_32x32x16_bf16(a11.v, B1u.v, D, 0, 0, 0);
            #pragma unroll
            for (int r = 0; r < 16; ++r) {
                int sh = 32 + (r & 3) + 8 * (r >> 2);
                float val = fmaxf(D[r] + b2c, 0.0f);
                bool ok = (vms >> sh) & 1ull;
                int ai = 8 + 2 * (r >> 2) + ((r & 3) >> 1);
                acc[ai] += ok ? val : 0.0f;
            }
        }

        *reinterpret_cast<uint4*>(&ywc[0]) = n0;
        *reinterpret_cast<uint4*>(&ywc[4]) = n1;
        *reinterpret_cast<uint4*>(&gwc[0]) = n2;
    }

    #pragma unroll
    for (int i = 0; i < 16; ++i) {
        int rb = i >> 3, rem = i & 7;
        int q2 = rem >> 1, u = rem & 1;
        int m = 16 * rb + 4 * q2 + 2 * hi + u;
        int dm = __shfl(dst, 2 * m, 64);
        if (dm >= 0) {
            out[(size_t)dm * IN_C + col]  = acc[i];
            conv[(size_t)dm * IN_C + col] = acc[i];
        }
    }
}

// ======================= non-MFMA fallbacks ==================================
template <int MODE>
__global__ __launch_bounds__(256) void k_nodes4(
    const float* __restrict__ x_dna, const float* __restrict__ v_dna,
    const float* __restrict__ x_prot, const float* __restrict__ v_prot,
    const float* __restrict__ prot_vec, const float* __restrict__ dna_vec,
    const float* __restrict__ W1, const float* __restrict__ b1,
    const float* __restrict__ W2, const float* __restrict__ b2,
    const int* __restrict__ node_order, const int* __restrict__ rowend,
    const int* __restrict__ counts, const int* __restrict__ pool_src,
    const int* __restrict__ pbs,
    const unsigned short* __restrict__ yp,
    int NP, float* __restrict__ out, float* __restrict__ conv, int NDp)
{
    int t = blockIdx.x * 256 + threadIdx.x;
    int pid = t >> 2;
    int sub = t & 3;
    if (pid >= NDp) return;

    int pb1 = pbs[1], pb2 = pbs[2], pb3 = pbs[3];
    int g = (pid >= pb1) + (pid >= pb2) + (pid >= pb3);
    int bb = __builtin_amdgcn_readfirstlane(g);

    int dst = node_order[pid];
    bool valid = (dst >= 0);
    int dsafe = valid ? dst : 0;

    int n_all = valid ? counts[dsafe] : 0;
    int start_all = valid ? (rowend[dsafe] - n_all) : 0;
    int nb4 = n_all >> 2, rem = n_all & 3;
    int n = nb4 + (sub < rem ? 1 : 0);
    int start = start_all + sub * nb4 + (sub < rem ? sub : rem);

    const float* Wa  = W1 + bb * (IN_F * IN_C);
    const float* Wp  = Wa + 32 * IN_C;
    const float* Wb  = W2 + bb * (IN_C * IN_C);
    const float* ba  = b1 + bb * IN_C;
    const float* bb2 = b2 + bb * IN_C;

    float vdx = v_dna[dsafe * 3 + 0], vdy = v_dna[dsafe * 3 + 1], vdz = v_dna[dsafe * 3 + 2];
    float nix = dna_vec[dsafe * 3 + 0], niy = dna_vec[dsafe * 3 + 1], niz = dna_vec[dsafe * 3 + 2];

    float h1b[IN_C];
    #pragma unroll
    for (int c = 0; c < IN_C; ++c) h1b[c] = ba[c];
    {
        const float4* xd = reinterpret_cast<const float4*>(x_dna + (size_t)dsafe * IN_C);
        #pragma unroll
        for (int kk = 0; kk < 8; ++kk) {
            float4 xv = xd[kk];
            float fs[4] = {xv.x, xv.y, xv.z, xv.w};
            #pragma unroll
            for (int j = 0; j < 4; ++j)
                #pragma unroll
                for (int c = 0; c < IN_C; ++c)
                    h1b[c] = fmaf(fs[j], Wa[(36 + kk * 4 + j) * IN_C + c], h1b[c]);
        }
    }

    float acc[IN_C];
    #pragma unroll
    for (int c = 0; c < IN_C; ++c) acc[c] = 0.0f;

    for (int k = 0; k < n; ++k) {
        int src = pool_src[start + k];
        float vpx = v_prot[src * 3 + 0], vpy = v_prot[src * 3 + 1], vpz = v_prot[src * 3 + 2];
        float njx = prot_vec[src * 3 + 0], njy = prot_vec[src * 3 + 1], njz = prot_vec[src * 3 + 2];
        float dx = vpx - vdx, dy = vpy - vdy, dz = vpz - vdz;
        float pf0 = sqrtf(dx * dx + dy * dy + dz * dz);
        float pf1 = angf(nix, niy, niz, dx, dy, dz);
        float pf2 = angf(njx, njy, njz, dx, dy, dz);
        float pf3 = angf(nix, niy, niz, njx, njy, njz);

        float h2[IN_C];
        #pragma unroll
        for (int c = 0; c < IN_C; ++c) h2[c] = bb2[c];

        if constexpr (MODE == 1) {
            unsigned yw[16];
            const uint4* ypv = reinterpret_cast<const uint4*>(yp + ((size_t)bb * NP + src) * IN_C);
            uint4 y0 = ypv[0], y1 = ypv[1], y2 = ypv[2], y3 = ypv[3];
            *reinterpret_cast<uint4*>(&yw[0])  = y0;
            *reinterpret_cast<uint4*>(&yw[4])  = y1;
            *reinterpret_cast<uint4*>(&yw[8])  = y2;
            *reinterpret_cast<uint4*>(&yw[12]) = y3;
            #pragma unroll
            for (int k2 = 0; k2 < IN_C; ++k2) {
                unsigned w = yw[k2 >> 1];
                float ypf = (k2 & 1) ? bfhi(w) : bflo(w);
                float h1v = h1b[k2] + ypf;
                h1v = fmaf(pf0, Wp[0 * IN_C + k2], h1v);
                h1v = fmaf(pf1, Wp[1 * IN_C + k2], h1v);
                h1v = fmaf(pf2, Wp[2 * IN_C + k2], h1v);
                h1v = fmaf(pf3, Wp[3 * IN_C + k2], h1v);
                float f = fmaxf(h1v, 0.0f);
                #pragma unroll
                for (int c = 0; c < IN_C; ++c)
                    h2[c] = fmaf(f, Wb[k2 * IN_C + c], h2[c]);
            }
        } else {
            float pf[4] = {pf0, pf1, pf2, pf3};
            const float4* xp = reinterpret_cast<const float4*>(x_prot + (size_t)src * IN_C);
            #pragma unroll
            for (int hh = 0; hh < 2; ++hh) {
                float h1h[16];
                #pragma unroll
                for (int c = 0; c < 16; ++c) h1h[c] = h1b[hh * 16 + c];
                #pragma unroll
                for (int kk = 0; kk < 8; ++kk) {
                    float4 xv = xp[kk];
                    float fs[4] = {xv.x, xv.y, xv.z, xv.w};
                    #pragma unroll
                    for (int j = 0; j < 4; ++j)
                        #pragma unroll
                        for (int c = 0; c < 16; ++c)
                            h1h[c] = fmaf(fs[j], Wa[(kk * 4 + j) * IN_C + hh * 16 + c], h1h[c]);
                }
                #pragma unroll
                for (int j = 0; j < 4; ++j)
                    #pragma unroll
                    for (int c = 0; c < 16; ++c)
                        h1h[c] = fmaf(pf[j], Wp[j * IN_C + hh * 16 + c], h1h[c]);
                #pragma unroll
                for (int k2 = 0; k2 < 16; ++k2) {
                    float f = fmaxf(h1h[k2], 0.0f);
                    #pragma unroll
                    for (int c = 0; c < IN_C; ++c)
                        h2[c] = fmaf(f, Wb[(hh * 16 + k2) * IN_C + c], h2[c]);
                }
            }
        }

        #pragma unroll
        for (int c = 0; c < IN_C; ++c)
            acc[c] += fmaxf(h2[c], 0.0f);
    }

    #pragma unroll
    for (int c = 0; c < IN_C; ++c)
        acc[c] += __shfl_xor(acc[c], 1, 64);
    #pragma unroll
    for (int c = 0; c < IN_C; ++c)
        acc[c] += __shfl_xor(acc[c], 2, 64);

    if (valid && sub < 2) {
        float* p = (sub ? conv : out) + (size_t)dst * IN_C;
        float4* p4 = reinterpret_cast<float4*>(p);
        #pragma unroll
        for (int qq = 0; qq < 8; ++qq) {
            float4 v;
            v.x = acc[qq * 4 + 0]; v.y = acc[qq * 4 + 1];
            v.z = acc[qq * 4 + 2]; v.w = acc[qq * 4 + 3];
            p4[qq] = v;
        }
    }
}

__global__ __launch_bounds__(256) void k_edges_fallback(
    const float* __restrict__ x_dna, const float* __restrict__ v_dna,
    const float* __restrict__ x_prot, const float* __restrict__ v_prot,
    const float* __restrict__ prot_vec, const float* __restrict__ dna_vec,
    const int* __restrict__ esrc, const int* __restrict__ edst,
    const float* __restrict__ W1, const float* __restrict__ b1,
    const float* __restrict__ W2, const float* __restrict__ b2,
    int E, float* __restrict__ conv)
{
    int t = blockIdx.x * blockDim.x + threadIdx.x;
    if (t >= E) return;
    int src = esrc[t], dst = edst[t];
    int b = branch_of(dst % 11);
    const float* Wa  = W1 + b * (IN_F * IN_C);
    const float* Wb  = W2 + b * (IN_C * IN_C);
    const float* ba  = b1 + b * IN_C;
    const float* bb2 = b2 + b * IN_C;

    float vdx = v_dna[dst * 3 + 0], vdy = v_dna[dst * 3 + 1], vdz = v_dna[dst * 3 + 2];
    float vpx = v_prot[src * 3 + 0], vpy = v_prot[src * 3 + 1], vpz = v_prot[src * 3 + 2];
    float nix = dna_vec[dst * 3 + 0], niy = dna_vec[dst * 3 + 1], niz = dna_vec[dst * 3 + 2];
    float njx = prot_vec[src * 3 + 0], njy = prot_vec[src * 3 + 1], njz = prot_vec[src * 3 + 2];
    float dx = vpx - vdx, dy = vpy - vdy, dz = vpz - vdz;
    float pf[4];
    pf[0] = sqrtf(dx * dx + dy * dy + dz * dz);
    pf[1] = angf(nix, niy, niz, dx, dy, dz);
    pf[2] = angf(njx, njy, njz, dx, dy, dz);
    pf[3] = angf(nix, niy, niz, njx, njy, njz);

    float h1[IN_C];
    #pragma unroll
    for (int c = 0; c < IN_C; ++c) h1[c] = ba[c];
    const float4* xp = reinterpret_cast<const float4*>(x_prot + (size_t)src * IN_C);
    #pragma unroll
    for (int kk = 0; kk < 8; ++kk) {
        float4 xv = xp[kk];
        float fs[4] = {xv.x, xv.y, xv.z, xv.w};
        #pragma unroll
        for (int j = 0; j < 4; ++j)
            #pragma unroll
            for (int c = 0; c < IN_C; ++c)
                h1[c] = fmaf(fs[j], Wa[(kk * 4 + j) * IN_C + c], h1[c]);
    }
    #pragma unroll
    for (int j = 0; j < 4; ++j)
        #pragma unroll
        for (int c = 0; c < IN_C; ++c)
            h1[c] = fmaf(pf[j], Wa[(32 + j) * IN_C + c], h1[c]);
    const float4* xd = reinterpret_cast<const float4*>(x_dna + (size_t)dst * IN_C);
    #pragma unroll
    for (int kk = 0; kk < 8; ++kk) {
        float4 xv = xd[kk];
        float fs[4] = {xv.x, xv.y, xv.z, xv.w};
        #pragma unroll
        for (int j = 0; j < 4; ++j)
            #pragma unroll
            for (int c = 0; c < IN_C; ++c)
                h1[c] = fmaf(fs[j], Wa[(36 + kk * 4 + j) * IN_C + c], h1[c]);
    }
    float h2[IN_C];
    #pragma unroll
    for (int c = 0; c < IN_C; ++c) h2[c] = bb2[c];
    #pragma unroll
    for (int k = 0; k < IN_C; ++k) {
        float f = fmaxf(h1[k], 0.0f);
        #pragma unroll
        for (int c = 0; c < IN_C; ++c)
            h2[c] = fmaf(f, Wb[k * IN_C + c], h2[c]);
    }
    float* cv = conv + (size_t)dst * IN_C;
    #pragma unroll
    for (int c = 0; c < IN_C; ++c)
        atomicAdd(&cv[c], fmaxf(h2[c], 0.0f));
}

extern "C" void kernel_launch(void* const* d_in, const int* in_sizes, int n_in,
                              void* d_out, int out_size, void* d_ws, size_t ws_size,
                              hipStream_t stream) {
    const float* x_dna    = (const float*)d_in[0];
    const float* v_dna    = (const float*)d_in[1];
    const float* x_prot   = (const float*)d_in[2];
    const float* v_prot   = (const float*)d_in[3];
    const float* prot_vec = (const float*)d_in[4];
    const float* dna_vec  = (const float*)d_in[5];
    const int*   esrc     = (const int*)d_in[6];
    const int*   edst     = (const int*)d_in[7];
    const float* W1       = (const float*)d_in[8];
    const float* b1       = (const float*)d_in[9];
    const float* W2       = (const float*)d_in[10];
    const float* b2       = (const float*)d_in[11];

    const int E  = in_sizes[6];
    const int ND = in_sizes[0] / IN_C;       // N_DNA
    const int NP = in_sizes[2] / IN_C;       // N_PROT
    const int half = out_size / 2;
    float* out  = (float*)d_out;
    float* conv = out + half;

    const int NDp = (ND + 160 + 31) & ~31;
    const int nblk_scan = (NDp + 1023) / 1024;
    const int eb = (E + 255) / 256;

    // ws: counts | hist(256) | gcur(512) | cur(256) | pbs(16) | blk(256)
    //     | rowcur | node_order | pool | yrec | drec
    const size_t base_ints = (size_t)ND + 256 + 512 + 256 + 16 + 256 + ND + NDp + E;
    const size_t ws_base   = base_ints * sizeof(int);
    const size_t yp_off    = (ws_base + 255) & ~(size_t)255;
    const size_t yrec_bytes = (size_t)NP * 4 * 64;                  // 64B/record
    const size_t ypb_bytes  = (size_t)NP * 4 * IN_C * 2;            // bf16 legacy
    const size_t yd_off    = yp_off + yrec_bytes;
    const size_t yd_bytes  = (size_t)ND * 128;                      // drec 128B/node

    if (ND == half / IN_C && ws_size >= ws_base && nblk_scan <= 256) {
        int* counts     = (int*)d_ws;          // ND
        int* hist       = counts + ND;         // 256
        int* gcur       = hist + 256;          // 512
        int* cur        = gcur + 512;          // 256
        int* pbs        = cur + 256;           // 16
        int* blk        = pbs + 16;            // 256 (legacy)
        int* rowcur     = blk + 256;           // ND  (rowend in fast path)
        int* node_order = rowcur + ND;         // NDp
        int* pool_src   = node_order + NDp;    // E
        unsigned*       yrec = (unsigned*)((char*)d_ws + yp_off);
        unsigned short* ypb  = (unsigned short*)((char*)d_ws + yp_off);  // legacy alias
        unsigned*       drec = (unsigned*)((char*)d_ws + yd_off);

        int mode = 0;
        if (ws_size >= yd_off + yd_bytes && ND % 11 == 0) mode = 2;
        else if (ws_size >= yp_off + ypb_bytes)           mode = 1;

        const int nbkt = (ND + (1 << BK_SHIFT) - 1) >> BK_SHIFT;
        const size_t stage_bytes = (size_t)nbkt * BCAP * sizeof(unsigned);
        const bool fastfill = (mode == 2) && (NP < (1 << 17)) && (nbkt <= NBKT_MAX)
                              && (stage_bytes <= yrec_bytes)
                              && (E / nbkt + 512 < BCAP);
        if (mode == 2 && !fastfill)
            mode = (ws_size >= yp_off + ypb_bytes) ? 1 : 0;   // record formats differ

        int NPpad = (NP + 63) & ~63;
        int NB = ND / 11;
        int NBpad = (NB + 63) & ~63;

        if (mode == 2) {
            unsigned* stage = yrec;   // overlay; dead after k_passB2
            hipMemsetAsync(hist, 0, 1024 * sizeof(int), stream);
            int na = (E + TILE_A - 1) / TILE_A;
            k_passA<<<na, 256, 0, stream>>>(esrc, edst, E, nbkt, gcur, stage);
            k_passB2<<<nbkt, 256, 0, stream>>>(stage, gcur, nbkt, ND,
                                               counts, rowcur, pool_src, hist);
            int nbA = (ND + 255) / 256;
            int totP = NPpad + 11 * NBpad;
            int nbP = (totP + 255) / 256;
            k_tail<<<nbA + nbP, 256, 0, stream>>>(
                counts, hist, cur, pbs, node_order, ND, nbA,
                x_prot, x_dna, v_prot, prot_vec, v_dna, dna_vec, W1, b1,
                NP, NPpad, NB, NBpad, yrec, drec);

            int nbm = (2 * NDp + 255) / 256;
            k_mfma<<<nbm, 256, 0, stream>>>(
                W1, W2, b2, node_order, rowcur, counts, pool_src, pbs,
                yrec, drec, NP, out, conv, NDp);
        } else {
            hipMemsetAsync(counts, 0, ((size_t)ND + 256) * sizeof(int), stream);
            k_count<<<eb, 256, 0, stream>>>(edst, E, counts);
            k_scan1<<<nblk_scan, 1024, 0, stream>>>(counts, ND, NDp, rowcur, blk,
                                                    hist, node_order);
            k_scan2<<<1, 256, 0, stream>>>(blk, nblk_scan);
            k_scan3<<<nblk_scan, 1024, 0, stream>>>(rowcur, blk, ND);
            k_fill<<<eb, 256, 0, stream>>>(esrc, edst, E, rowcur, pool_src);
            k_padscan2<<<1, 256, 0, stream>>>(hist, pbs);
            k_assign<<<(ND + 255) / 256, 256, 0, stream>>>(counts, ND, hist,
                                                           node_order);
            if (mode == 1) {
                int tot = 4 * NPpad;
                k_precomp1<<<(tot + 255) / 256, 256, 0, stream>>>(
                    x_prot, W1, NP, NPpad, ypb);
                int nb4 = (4 * NDp + 255) / 256;
                k_nodes4<1><<<nb4, 256, 0, stream>>>(
                    x_dna, v_dna, x_prot, v_prot, prot_vec, dna_vec,
                    W1, b1, W2, b2, node_order, rowcur, counts, pool_src, pbs,
                    ypb, NP, out, conv, NDp);
            } else {
                int nb4 = (4 * NDp + 255) / 256;
                k_nodes4<0><<<nb4, 256, 0, stream>>>(
                    x_dna, v_dna, x_prot, v_prot, prot_vec, dna_vec,
                    W1, b1, W2, b2, node_order, rowcur, counts, pool_src, pbs,
                    nullptr, NP, out, conv, NDp);
            }
        }
    } else {
        hipMemsetAsync(conv, 0, (size_t)half * sizeof(float), stream);
        k_edges_fallback<<<eb, 256, 0, stream>>>(
            x_dna, v_dna, x_prot, v_prot, prot_vec, dna_vec,
            esrc, edst, W1, b1, W2, b2, E, conv);
        hipMemcpyAsync(out, conv, (size_t)half * sizeof(float),
                       hipMemcpyDeviceToDevice, stream);
    }
}